// Round 4
// baseline (11972.279 us; speedup 1.0000x reference)
//
#include <hip/hip_runtime.h>
#include <hip/hip_bf16.h>
#include <cmath>

typedef __bf16 bf;
typedef __bf16 bfrag __attribute__((ext_vector_type(8)));
typedef float  f32x4 __attribute__((ext_vector_type(4)));

constexpr int BSZ = 32, SEQ = 512, NVAR = 862, NMARK = 4, NTOK = 866;
constexpr int DM = 512, DS = 16, DTR = 32, DFF = 512, NL = 4, PRED = 96;
constexpr int M = BSZ * NTOK;              // 27712 tokens
constexpr float EPS = 1e-5f;

// ---------------------------------------------------------------- f32 -> bf16
__global__ void cvt_kernel(const float* __restrict__ src, bf* __restrict__ dst, int n4) {
    int i = blockIdx.x * 256 + threadIdx.x;
    if (i >= n4) return;
    f32x4 v = ((const f32x4*)src)[i];
    bf o[4];
    o[0] = (bf)v[0]; o[1] = (bf)v[1]; o[2] = (bf)v[2]; o[3] = (bf)v[3];
    *(uint2*)&dst[i * 4] = *(uint2*)o;
}

// ---------------------------------------------------------------- mean / std
__global__ void meanstd_kernel(const float* __restrict__ xe,
                               float* __restrict__ mean, float* __restrict__ stdv) {
    int v = blockIdx.x * 256 + threadIdx.x;
    int b = blockIdx.y;
    if (v >= NVAR) return;
    const float* p = xe + (size_t)b * SEQ * NVAR + v;
    float s = 0.f, sq = 0.f;
#pragma unroll 4
    for (int t = 0; t < SEQ; t++) {
        float x = p[(size_t)t * NVAR];
        s += x; sq += x * x;
    }
    float mu = s * (1.f / SEQ);
    float var = sq * (1.f / SEQ) - mu * mu;
    mean[b * NVAR + v] = mu;
    stdv[b * NVAR + v] = sqrtf(var + EPS);
}

// ------------------------------------------------- tok build (transpose+norm)
__global__ void tok_kernel(const float* __restrict__ xe, const float* __restrict__ xm,
                           const float* __restrict__ mean, const float* __restrict__ stdv,
                           bf* __restrict__ tok) {
    __shared__ float tile[32][33];
    int b = blockIdx.z;
    int v0 = blockIdx.x * 32, s0 = blockIdx.y * 32;
    int tx = threadIdx.x, ty = threadIdx.y;  // 32 x 8
    int v = v0 + tx;
    float mu = 0.f, rs = 0.f;
    if (v < NVAR) { mu = mean[b * NVAR + v]; rs = 1.f / stdv[b * NVAR + v]; }
#pragma unroll
    for (int j = 0; j < 4; j++) {
        int s = s0 + ty + j * 8;
        float val = 0.f;
        if (v < NVAR)       val = (xe[((size_t)b * SEQ + s) * NVAR + v] - mu) * rs;
        else if (v < NTOK)  val = xm[((size_t)b * SEQ + s) * NMARK + (v - NVAR)];
        tile[ty + j * 8][tx] = val;
    }
    __syncthreads();
#pragma unroll
    for (int j = 0; j < 4; j++) {
        int n = v0 + ty + j * 8;
        if (n < NTOK)
            tok[((size_t)b * NTOK + n) * SEQ + s0 + tx] = (bf)tile[tx][ty + j * 8];
    }
}

// ---------------------------------------------------------------- GEMM
// C[M,N] = A[M,K](bf16) * W[N,K]^T (bf16), f32 accumulate.
// ksplit: K-split for BOTH A (A0/A1) and W (W0/W1) at k=ksplit.
template <int BN, int ACT, bool BIAS, bool RES, bool HEAD, typename CT>
__global__ __launch_bounds__(256, 2) void gemm_kernel(
    const bf* __restrict__ A0, const bf* __restrict__ A1,
    const bf* __restrict__ W0, const bf* __restrict__ W1,
    CT* __restrict__ C, const float* __restrict__ bias, const bf* __restrict__ res,
    int Mreal, int Nreal, int K, int lda, int ldw, int ksplit, int ldc,
    size_t sAz, size_t sWz, size_t sCz,
    const float* __restrict__ mean, const float* __restrict__ stdv) {
    constexpr int BM = 128, BK = 64, SK = BK + 8;
    constexpr int NT = BN / 32;
    constexpr int ACH = BM * BK / 8 / 256;   // 4
    constexpr int BCH = BN * BK / 8 / 256;   // 4 or 2
    __shared__ __align__(16) bf Als[BM * SK];
    __shared__ __align__(16) bf Bls[BN * SK];

    int z = blockIdx.z;
    A0 += (size_t)z * sAz; W0 += (size_t)z * sWz; C += (size_t)z * sCz;
    int m0 = blockIdx.x * BM, n0 = blockIdx.y * BN;
    int tid = threadIdx.x, lane = tid & 63, wave = tid >> 6;
    int wm = wave >> 1, wn = wave & 1;
    int q = lane >> 4, ml = lane & 15;
    int rloc = tid >> 3, c8 = (tid & 7) * 8;

    f32x4 acc[4][NT];
#pragma unroll
    for (int i = 0; i < 4; i++)
#pragma unroll
        for (int j = 0; j < NT; j++) { acc[i][j][0] = 0.f; acc[i][j][1] = 0.f; acc[i][j][2] = 0.f; acc[i][j][3] = 0.f; }

    for (int kt = 0; kt < K; kt += BK) {
        int4 ra[ACH], rb[BCH];
        {
            const bf* abase = (ksplit && kt >= ksplit) ? (A1 + (kt - ksplit)) : (A0 + kt);
#pragma unroll
            for (int i = 0; i < ACH; i++) {
                int gm = m0 + rloc + i * 32;
                if (gm < Mreal) ra[i] = *(const int4*)(abase + (size_t)gm * lda + c8);
                else            ra[i] = int4{0, 0, 0, 0};
            }
        }
        {
            const bf* wsrc = (ksplit && kt >= ksplit) ? (W1 + (kt - ksplit)) : (W0 + kt);
#pragma unroll
            for (int i = 0; i < BCH; i++) {
                int r = rloc + i * 32;
                if (n0 + r < Nreal) rb[i] = *(const int4*)(wsrc + (size_t)(n0 + r) * ldw + c8);
                else                rb[i] = int4{0, 0, 0, 0};
            }
        }
        __syncthreads();
#pragma unroll
        for (int i = 0; i < ACH; i++) *(int4*)&Als[(rloc + i * 32) * SK + c8] = ra[i];
#pragma unroll
        for (int i = 0; i < BCH; i++) *(int4*)&Bls[(rloc + i * 32) * SK + c8] = rb[i];
        __syncthreads();
#pragma unroll
        for (int kk = 0; kk < BK; kk += 32) {
            bfrag af[4], bff[NT];
#pragma unroll
            for (int i = 0; i < 4; i++)
                af[i] = *(bfrag*)&Als[(wm * 64 + i * 16 + ml) * SK + kk + q * 8];
#pragma unroll
            for (int j = 0; j < NT; j++)
                bff[j] = *(bfrag*)&Bls[(wn * (BN / 2) + j * 16 + ml) * SK + kk + q * 8];
#pragma unroll
            for (int i = 0; i < 4; i++)
#pragma unroll
                for (int j = 0; j < NT; j++)
                    acc[i][j] = __builtin_amdgcn_mfma_f32_16x16x32_bf16(af[i], bff[j], acc[i][j], 0, 0, 0);
        }
        __syncthreads();
    }

#pragma unroll
    for (int j = 0; j < NT; j++) {
        int col = n0 + wn * (BN / 2) + j * 16 + ml;
        float bv = 0.f;
        if (BIAS && col < Nreal) bv = bias[col];
#pragma unroll
        for (int i = 0; i < 4; i++) {
            int rowb = m0 + wm * 64 + i * 16 + q * 4;
#pragma unroll
            for (int r = 0; r < 4; r++) {
                int row = rowb + r;
                if (row >= Mreal || col >= Nreal) continue;
                float x = acc[i][j][r] + bv;
                if (ACT == 1) x = 0.5f * x * (1.f + erff(x * 0.70710678118654752f));
                if (RES)      x += (float)res[(size_t)row * DM + col];
                if (HEAD) {
                    int bidx = row / NTOK, n = row - bidx * NTOK;
                    if (n < NVAR) {
                        float sc = stdv[bidx * NVAR + n], mm = mean[bidx * NVAR + n];
                        C[((size_t)bidx * PRED + col) * NVAR + n] = (CT)(x * sc + mm);
                    }
                } else {
                    C[(size_t)row * ldc + col] = (CT)x;
                }
            }
        }
    }
    if (HEAD && blockIdx.x == 0 && blockIdx.y == 0 && tid == 0)
        C[(size_t)BSZ * PRED * NVAR] = (CT)0.f;  // loss_reg = 0
}

// ---------------------------------------------------------------- conv + silu
// fwd (dir=0): xc[l] = silu(x[l-1]*w0 + x[l]*w1 + cb)
// rev (dir=1): xc[l] = silu(x[l+1]*w0 + x[l]*w1 + cb)
// xz chunk layout per token: [x_f(512) z_f(512) x_r(512) z_r(512)]
__global__ void conv_kernel(const bf* __restrict__ xz, const float* __restrict__ cw,
                            const float* __restrict__ cb, bf* __restrict__ xc, int Mc) {
    int id = blockIdx.x * 256 + threadIdx.x;   // 2*Mc*64 total
    int dir = id / (Mc * 64); int rem = id - dir * (Mc * 64);
    int token = rem >> 6; int ch0 = (rem & 63) * 8;
    int t = token % NTOK;
    const bf* xb = xz + (size_t)token * (4 * DM) + dir * (2 * DM) + ch0;
    bfrag xt = *(const bfrag*)xb;
    bfrag xn;
#pragma unroll
    for (int i = 0; i < 8; i++) xn[i] = (bf)0.f;
    int tn = dir ? t + 1 : t - 1;
    if ((unsigned)tn < (unsigned)NTOK)
        xn = *(const bfrag*)(xb + (dir ? (4 * DM) : -(4 * DM)));
    const float2* cwp = (const float2*)cw + ((size_t)dir * DM + ch0);
    const float*  cbp = cb + (size_t)dir * DM + ch0;
    bfrag ov;
#pragma unroll
    for (int jj = 0; jj < 8; jj++) {
        float2 w = cwp[jj];
        float x = (float)xn[jj] * w.x + (float)xt[jj] * w.y + cbp[jj];
        x = x / (1.f + __expf(-x));
        ov[jj] = (bf)x;
    }
    *(bfrag*)(xc + (size_t)dir * Mc * DM + (size_t)token * DM + ch0) = ov;
}

// ---------------------------------------------------------------- fused scan
// One lane = one channel d. dt = softplus(dbc[:32]·Wdt[d] + bdt), 16-state SSM
// recurrence, y = (scan + D*x)*silu(z) written to ycc[token][dir*512 + d].
__global__ __launch_bounds__(64) void scan_kernel(
    const float* __restrict__ dbc, const bf* __restrict__ xc, const bf* __restrict__ xz,
    const float* __restrict__ Wdt, const float* __restrict__ bdt,
    const float* __restrict__ Alog, const float* __restrict__ Dp,
    bf* __restrict__ y, int Mc) {
    int lane = threadIdx.x;
    int dg = blockIdx.x, b = blockIdx.y, dir = blockIdx.z;
    int d = dg * 64 + lane;
    int dd = dir * DM + d;
    float wdt[32];
    {
        const f32x4* wp = (const f32x4*)(Wdt + (size_t)dd * DTR);
#pragma unroll
        for (int i = 0; i < 8; i++) {
            f32x4 v = wp[i];
            wdt[i * 4 + 0] = v[0]; wdt[i * 4 + 1] = v[1]; wdt[i * 4 + 2] = v[2]; wdt[i * 4 + 3] = v[3];
        }
    }
    float A2[16];
    {
        const f32x4* ap = (const f32x4*)(Alog + (size_t)dd * DS);
#pragma unroll
        for (int i = 0; i < 4; i++) {
            f32x4 v = ap[i];
#pragma unroll
            for (int jj = 0; jj < 4; jj++)
                A2[i * 4 + jj] = -__expf(v[jj]) * 1.4426950408889634f;  // *log2e
        }
    }
    float bdtv = bdt[dd];
    float Dd = Dp[dd];
    float h[16];
#pragma unroll
    for (int s = 0; s < 16; s++) h[s] = 0.f;

    for (int t = 0; t < NTOK; t++) {
        int l = dir ? (NTOK - 1 - t) : t;
        size_t token = (size_t)b * NTOK + l;
        const float* bc = dbc + ((size_t)dir * Mc + token) * 64;
        float qv[64];
        {
            const f32x4* p4 = (const f32x4*)bc;
#pragma unroll
            for (int i = 0; i < 16; i++) {
                f32x4 v = p4[i];
                qv[i * 4 + 0] = v[0]; qv[i * 4 + 1] = v[1]; qv[i * 4 + 2] = v[2]; qv[i * 4 + 3] = v[3];
            }
        }
        float a0 = bdtv, a1 = 0.f, a2 = 0.f, a3 = 0.f;
#pragma unroll
        for (int r = 0; r < 32; r += 4) {
            a0 += qv[r + 0] * wdt[r + 0];
            a1 += qv[r + 1] * wdt[r + 1];
            a2 += qv[r + 2] * wdt[r + 2];
            a3 += qv[r + 3] * wdt[r + 3];
        }
        float dtl = (a0 + a1) + (a2 + a3);
        float dt = (dtl > 20.f) ? dtl : log1pf(__expf(dtl));
        float x = (float)xc[(size_t)dir * Mc * DM + token * DM + d];
        float zv = (float)xz[token * (4 * DM) + dir * (2 * DM) + DM + d];
        float dtx = dt * x;
        float yv = 0.f;
#pragma unroll
        for (int s = 0; s < 16; s++) {
            float a = exp2f(dt * A2[s]);
            h[s] = a * h[s] + dtx * qv[32 + s];
            yv += qv[48 + s] * h[s];
        }
        float sz = zv / (1.f + __expf(-zv));
        y[token * (2 * DM) + dir * DM + d] = (bf)((yv + Dd * x) * sz);
    }
}

// ---------------------------------------------------------------- LayerNorm
__global__ __launch_bounds__(256) void ln_kernel(const bf* X, bf* Y,
                                                 const float* __restrict__ g, const float* __restrict__ bb) {
    int token = blockIdx.x * 4 + (threadIdx.x >> 6);
    int lane = threadIdx.x & 63;
    bfrag xv = *(const bfrag*)(X + (size_t)token * DM + lane * 8);
    float xf[8]; float s = 0.f, sq = 0.f;
#pragma unroll
    for (int j = 0; j < 8; j++) { xf[j] = (float)xv[j]; s += xf[j]; sq += xf[j] * xf[j]; }
#pragma unroll
    for (int o = 1; o < 64; o <<= 1) { s += __shfl_xor(s, o); sq += __shfl_xor(sq, o); }
    float mu = s * (1.f / DM);
    float rs = rsqrtf(sq * (1.f / DM) - mu * mu + EPS);
    f32x4 g0 = ((const f32x4*)g)[lane * 2], g1 = ((const f32x4*)g)[lane * 2 + 1];
    f32x4 b0 = ((const f32x4*)bb)[lane * 2], b1 = ((const f32x4*)bb)[lane * 2 + 1];
    bfrag ov;
#pragma unroll
    for (int j = 0; j < 8; j++) {
        float gg = (j < 4) ? g0[j] : g1[j - 4];
        float bbv = (j < 4) ? b0[j] : b1[j - 4];
        ov[j] = (bf)((xf[j] - mu) * rs * gg + bbv);
    }
    *(bfrag*)(Y + (size_t)token * DM + lane * 8) = ov;
}

// ---------------------------------------------------------------- launch
extern "C" void kernel_launch(void* const* d_in, const int* in_sizes, int n_in,
                              void* d_out, int out_size, void* d_ws, size_t ws_size,
                              hipStream_t stream) {
    const float* x_enc = (const float*)d_in[0];
    const float* x_mark = (const float*)d_in[1];
    const float* W_emb = (const float*)d_in[4];
    const float* b_emb = (const float*)d_in[5];
    const float* mWin = (const float*)d_in[6];
    const float* mcw = (const float*)d_in[7];
    const float* mcb = (const float*)d_in[8];
    const float* mWx = (const float*)d_in[9];
    const float* mWdt = (const float*)d_in[10];
    const float* mbdt = (const float*)d_in[11];
    const float* mAlog = (const float*)d_in[12];
    const float* mD = (const float*)d_in[13];
    const float* mWout = (const float*)d_in[14];
    const float* W1w = (const float*)d_in[15];
    const float* b1w = (const float*)d_in[16];
    const float* W2w = (const float*)d_in[17];
    const float* b2w = (const float*)d_in[18];
    const float* ln1g = (const float*)d_in[19];
    const float* ln1b = (const float*)d_in[20];
    const float* ln2g = (const float*)d_in[21];
    const float* ln2b = (const float*)d_in[22];
    const float* lnfg = (const float*)d_in[23];
    const float* lnfb = (const float*)d_in[24];
    const float* headW = (const float*)d_in[25];
    const float* headb = (const float*)d_in[26];

    auto a256 = [](size_t x) { return (x + 255) & ~(size_t)255; };
    char* ws = (char*)d_ws;
    size_t off = 0;
    auto alloc = [&](size_t n) { size_t r = off; off += a256(n); return ws + r; };
    float* mean = (float*)alloc((size_t)BSZ * NVAR * 4);
    float* stdv = (float*)alloc((size_t)BSZ * NVAR * 4);
    bf* h  = (bf*)alloc((size_t)M * DM * 2);
    bf* t1 = (bf*)alloc((size_t)M * DM * 2);   // tok / hsum / ff
    bf* t2 = (bf*)alloc((size_t)M * DM * 2);   // h2
    // bf16-converted GEMM weights
    constexpr int nEmb = 512 * 512, nWin = NL * 2 * 1024 * 512, nWx = NL * 2 * 64 * 512,
                  nWout = NL * 2 * 512 * 512, nW1 = NL * DFF * DM, nW2 = NL * DM * DFF,
                  nHead = PRED * DM;
    bf* wEmb  = (bf*)alloc((size_t)nEmb * 2);
    bf* wWin  = (bf*)alloc((size_t)nWin * 2);
    bf* wWx   = (bf*)alloc((size_t)nWx * 2);
    bf* wWout = (bf*)alloc((size_t)nWout * 2);
    bf* wW1   = (bf*)alloc((size_t)nW1 * 2);
    bf* wW2   = (bf*)alloc((size_t)nW2 * 2);
    bf* wHead = (bf*)alloc((size_t)nHead * 2);
    size_t fixedEnd = off;

    // adaptive chunk size: CB batches per chunk
    // chunk bytes: xz(Mc*2048*2) + xc(2*Mc*512*2) + dbc(2*Mc*64*4) + y(Mc*1024*2)
    int CB = 1;
    {
        int cbs[6] = {32, 16, 8, 4, 2, 1};
        for (int i = 0; i < 6; i++) {
            size_t mc = (size_t)cbs[i] * NTOK;
            size_t chunkB = a256(mc * 4096) + a256(mc * 2048) + a256(mc * 512) + a256(mc * 2048);
            if (fixedEnd + chunkB <= ws_size) { CB = cbs[i]; break; }
        }
    }
    const size_t Mc = (size_t)CB * NTOK;
    size_t co = fixedEnd;
    bf* xzc = (bf*)(ws + co);    co += a256(Mc * 4096);
    bf* xcc = (bf*)(ws + co);    co += a256(Mc * 2048);
    float* dbcc = (float*)(ws + co); co += a256(Mc * 512);
    bf* ycc = (bf*)(ws + co);
    const int NC = BSZ / CB;
    const int MTc = (int)((Mc + 127) / 128);
    constexpr int MT = (M + 127) / 128;  // 217

    // weight conversion f32 -> bf16
    cvt_kernel<<<(nEmb / 4 + 255) / 256, 256, 0, stream>>>(W_emb, wEmb, nEmb / 4);
    cvt_kernel<<<(nWin / 4 + 255) / 256, 256, 0, stream>>>(mWin, wWin, nWin / 4);
    cvt_kernel<<<(nWx / 4 + 255) / 256, 256, 0, stream>>>(mWx, wWx, nWx / 4);
    cvt_kernel<<<(nWout / 4 + 255) / 256, 256, 0, stream>>>(mWout, wWout, nWout / 4);
    cvt_kernel<<<(nW1 / 4 + 255) / 256, 256, 0, stream>>>(W1w, wW1, nW1 / 4);
    cvt_kernel<<<(nW2 / 4 + 255) / 256, 256, 0, stream>>>(W2w, wW2, nW2 / 4);
    cvt_kernel<<<(nHead / 4 + 255) / 256, 256, 0, stream>>>(headW, wHead, nHead / 4);

    meanstd_kernel<<<dim3(4, BSZ), 256, 0, stream>>>(x_enc, mean, stdv);
    tok_kernel<<<dim3(28, 16, BSZ), dim3(32, 8), 0, stream>>>(x_enc, x_mark, mean, stdv, t1);
    // embedding: h = tok · W_emb^T + b_emb
    gemm_kernel<128, 0, true, false, false, bf><<<dim3(MT, 4), 256, 0, stream>>>(
        t1, nullptr, wEmb, nullptr, h, b_emb, nullptr,
        M, DM, SEQ, SEQ, SEQ, 0, DM, 0, 0, 0, nullptr, nullptr);

    for (int l = 0; l < NL; l++) {
        const bf* Winl = wWin + (size_t)l * 2 * 1024 * 512;
        const float* cwl = mcw + (size_t)l * 2 * DM * 2;
        const float* cbl = mcb + (size_t)l * 2 * DM;
        const bf* Wxl = wWx + (size_t)l * 2 * 64 * 512;
        const float* Wdtl = mWdt + (size_t)l * 2 * 512 * 32;
        const float* bdtl = mbdt + (size_t)l * 2 * DM;
        const float* Alogl = mAlog + (size_t)l * 2 * 512 * 16;
        const float* Dl = mD + (size_t)l * 2 * DM;
        const bf* Woutl = wWout + (size_t)l * 2 * 512 * 512;
        const bf* W1l = wW1 + (size_t)l * DFF * DM;
        const bf* W2l = wW2 + (size_t)l * DM * DFF;

        for (int c = 0; c < NC; c++) {
            size_t coff = (size_t)c * Mc;  // token offset
            // xz = h · [Win_f ; Win_r]^T   (N = 2048)
            gemm_kernel<128, 0, false, false, false, bf><<<dim3(MTc, 16), 256, 0, stream>>>(
                h + coff * DM, nullptr, Winl, nullptr, xzc, nullptr, nullptr,
                (int)Mc, 2048, 512, 512, 512, 0, 2048, 0, 0, 0, nullptr, nullptr);
            // conv + silu (both directions)
            conv_kernel<<<(int)(2 * Mc * 64 / 256), 256, 0, stream>>>(xzc, cwl, cbl, xcc, (int)Mc);
            // dbc = xc · Wx^T  (z-batched over dirs, N=64, f32 out)
            gemm_kernel<64, 0, false, false, false, float><<<dim3(MTc, 1, 2), 256, 0, stream>>>(
                xcc, nullptr, Wxl, nullptr, dbcc, nullptr, nullptr,
                (int)Mc, 64, 512, 512, 512, 0, 64,
                Mc * 512, (size_t)64 * 512, Mc * 64, nullptr, nullptr);
            // fused dt-proj + softplus + SSM scan + gate -> ycc
            scan_kernel<<<dim3(8, CB, 2), 64, 0, stream>>>(
                dbcc, xcc, xzc, Wdtl, bdtl, Alogl, Dl, ycc, (int)Mc);
            // hsum = h + y_f·Wout_f^T + y_r·Wout_r^T  (K=1024, split at 512)
            gemm_kernel<128, 0, false, true, false, bf><<<dim3(MTc, 4), 256, 0, stream>>>(
                ycc, ycc + 512, Woutl, Woutl + 512 * 512, t1 + coff * DM, nullptr, h + coff * DM,
                (int)Mc, DM, 1024, 1024, 512, 512, DM, 0, 0, 0, nullptr, nullptr);
        }
        ln_kernel<<<M / 4, 256, 0, stream>>>(t1, t2, ln1g + l * DM, ln1b + l * DM);
        // FFN
        gemm_kernel<128, 1, true, false, false, bf><<<dim3(MT, 4), 256, 0, stream>>>(
            t2, nullptr, W1l, nullptr, t1, b1w + l * DFF, nullptr,
            M, DFF, DM, DM, DM, 0, DFF, 0, 0, 0, nullptr, nullptr);
        gemm_kernel<128, 0, true, true, false, bf><<<dim3(MT, 4), 256, 0, stream>>>(
            t1, nullptr, W2l, nullptr, h, b2w + l * DM, t2,
            M, DM, DFF, DFF, DFF, 0, DM, 0, 0, 0, nullptr, nullptr);
        ln_kernel<<<M / 4, 256, 0, stream>>>(h, h, ln2g + l * DM, ln2b + l * DM);
    }

    ln_kernel<<<M / 4, 256, 0, stream>>>(h, t1, lnfg, lnfb);
    // head + de-normalize + scatter to (B, PRED, NVAR), plus loss scalar
    gemm_kernel<128, 0, true, false, true, float><<<dim3(MT, 1), 256, 0, stream>>>(
        t1, nullptr, wHead, nullptr, (float*)d_out, headb, nullptr,
        M, PRED, DM, DM, DM, 0, 1, 0, 0, 0, mean, stdv);
}

// Round 5
// 7963.521 us; speedup vs baseline: 1.5034x; 1.5034x over previous
//
#include <hip/hip_runtime.h>
#include <hip/hip_bf16.h>
#include <cmath>

typedef __bf16 bf;
typedef __bf16 bfrag __attribute__((ext_vector_type(8)));
typedef float  f32x4 __attribute__((ext_vector_type(4)));

constexpr int BSZ = 32, SEQ = 512, NVAR = 862, NMARK = 4, NTOK = 866;
constexpr int DM = 512, DS = 16, DTR = 32, DFF = 512, NL = 4, PRED = 96;
constexpr int M = BSZ * NTOK;              // 27712 tokens
constexpr float EPS = 1e-5f;

// ---------------------------------------------------------------- f32 -> bf16
__global__ void cvt_kernel(const float* __restrict__ src, bf* __restrict__ dst, int n4) {
    int i = blockIdx.x * 256 + threadIdx.x;
    if (i >= n4) return;
    f32x4 v = ((const f32x4*)src)[i];
    bf o[4];
    o[0] = (bf)v[0]; o[1] = (bf)v[1]; o[2] = (bf)v[2]; o[3] = (bf)v[3];
    *(uint2*)&dst[i * 4] = *(uint2*)o;
}

// ---------------------------------------------------------------- mean / std
__global__ void meanstd_kernel(const float* __restrict__ xe,
                               float* __restrict__ mean, float* __restrict__ stdv) {
    int v = blockIdx.x * 256 + threadIdx.x;
    int b = blockIdx.y;
    if (v >= NVAR) return;
    const float* p = xe + (size_t)b * SEQ * NVAR + v;
    float s = 0.f, sq = 0.f;
#pragma unroll 4
    for (int t = 0; t < SEQ; t++) {
        float x = p[(size_t)t * NVAR];
        s += x; sq += x * x;
    }
    float mu = s * (1.f / SEQ);
    float var = sq * (1.f / SEQ) - mu * mu;
    mean[b * NVAR + v] = mu;
    stdv[b * NVAR + v] = sqrtf(var + EPS);
}

// ------------------------------------------------- tok build (transpose+norm)
__global__ void tok_kernel(const float* __restrict__ xe, const float* __restrict__ xm,
                           const float* __restrict__ mean, const float* __restrict__ stdv,
                           bf* __restrict__ tok) {
    __shared__ float tile[32][33];
    int b = blockIdx.z;
    int v0 = blockIdx.x * 32, s0 = blockIdx.y * 32;
    int tx = threadIdx.x, ty = threadIdx.y;  // 32 x 8
    int v = v0 + tx;
    float mu = 0.f, rs = 0.f;
    if (v < NVAR) { mu = mean[b * NVAR + v]; rs = 1.f / stdv[b * NVAR + v]; }
#pragma unroll
    for (int j = 0; j < 4; j++) {
        int s = s0 + ty + j * 8;
        float val = 0.f;
        if (v < NVAR)       val = (xe[((size_t)b * SEQ + s) * NVAR + v] - mu) * rs;
        else if (v < NTOK)  val = xm[((size_t)b * SEQ + s) * NMARK + (v - NVAR)];
        tile[ty + j * 8][tx] = val;
    }
    __syncthreads();
#pragma unroll
    for (int j = 0; j < 4; j++) {
        int n = v0 + ty + j * 8;
        if (n < NTOK)
            tok[((size_t)b * NTOK + n) * SEQ + s0 + tx] = (bf)tile[tx][ty + j * 8];
    }
}

// ---------------------------------------------------------------- GEMM
// C[M,N] = A[M,K](bf16) * W[N,K]^T (bf16), f32 accumulate.
// ksplit: K-split for BOTH A (A0/A1) and W (W0/W1) at k=ksplit.
template <int BN, int ACT, bool BIAS, bool RES, bool HEAD, typename CT>
__global__ __launch_bounds__(256, 2) void gemm_kernel(
    const bf* __restrict__ A0, const bf* __restrict__ A1,
    const bf* __restrict__ W0, const bf* __restrict__ W1,
    CT* __restrict__ C, const float* __restrict__ bias, const bf* __restrict__ res,
    int Mreal, int Nreal, int K, int lda, int ldw, int ksplit, int ldc,
    size_t sAz, size_t sWz, size_t sCz,
    const float* __restrict__ mean, const float* __restrict__ stdv) {
    constexpr int BM = 128, BK = 64, SK = BK + 8;
    constexpr int NT = BN / 32;
    constexpr int ACH = BM * BK / 8 / 256;   // 4
    constexpr int BCH = BN * BK / 8 / 256;   // 4 or 2
    __shared__ __align__(16) bf Als[BM * SK];
    __shared__ __align__(16) bf Bls[BN * SK];

    int z = blockIdx.z;
    A0 += (size_t)z * sAz; W0 += (size_t)z * sWz; C += (size_t)z * sCz;
    int m0 = blockIdx.x * BM, n0 = blockIdx.y * BN;
    int tid = threadIdx.x, lane = tid & 63, wave = tid >> 6;
    int wm = wave >> 1, wn = wave & 1;
    int q = lane >> 4, ml = lane & 15;
    int rloc = tid >> 3, c8 = (tid & 7) * 8;

    f32x4 acc[4][NT];
#pragma unroll
    for (int i = 0; i < 4; i++)
#pragma unroll
        for (int j = 0; j < NT; j++) { acc[i][j][0] = 0.f; acc[i][j][1] = 0.f; acc[i][j][2] = 0.f; acc[i][j][3] = 0.f; }

    for (int kt = 0; kt < K; kt += BK) {
        int4 ra[ACH], rb[BCH];
        {
            const bf* abase = (ksplit && kt >= ksplit) ? (A1 + (kt - ksplit)) : (A0 + kt);
#pragma unroll
            for (int i = 0; i < ACH; i++) {
                int gm = m0 + rloc + i * 32;
                if (gm < Mreal) ra[i] = *(const int4*)(abase + (size_t)gm * lda + c8);
                else            ra[i] = int4{0, 0, 0, 0};
            }
        }
        {
            const bf* wsrc = (ksplit && kt >= ksplit) ? (W1 + (kt - ksplit)) : (W0 + kt);
#pragma unroll
            for (int i = 0; i < BCH; i++) {
                int r = rloc + i * 32;
                if (n0 + r < Nreal) rb[i] = *(const int4*)(wsrc + (size_t)(n0 + r) * ldw + c8);
                else                rb[i] = int4{0, 0, 0, 0};
            }
        }
        __syncthreads();
#pragma unroll
        for (int i = 0; i < ACH; i++) *(int4*)&Als[(rloc + i * 32) * SK + c8] = ra[i];
#pragma unroll
        for (int i = 0; i < BCH; i++) *(int4*)&Bls[(rloc + i * 32) * SK + c8] = rb[i];
        __syncthreads();
#pragma unroll
        for (int kk = 0; kk < BK; kk += 32) {
            bfrag af[4], bff[NT];
#pragma unroll
            for (int i = 0; i < 4; i++)
                af[i] = *(bfrag*)&Als[(wm * 64 + i * 16 + ml) * SK + kk + q * 8];
#pragma unroll
            for (int j = 0; j < NT; j++)
                bff[j] = *(bfrag*)&Bls[(wn * (BN / 2) + j * 16 + ml) * SK + kk + q * 8];
#pragma unroll
            for (int i = 0; i < 4; i++)
#pragma unroll
                for (int j = 0; j < NT; j++)
                    acc[i][j] = __builtin_amdgcn_mfma_f32_16x16x32_bf16(af[i], bff[j], acc[i][j], 0, 0, 0);
        }
        __syncthreads();
    }

#pragma unroll
    for (int j = 0; j < NT; j++) {
        int col = n0 + wn * (BN / 2) + j * 16 + ml;
        float bv = 0.f;
        if (BIAS && col < Nreal) bv = bias[col];
#pragma unroll
        for (int i = 0; i < 4; i++) {
            int rowb = m0 + wm * 64 + i * 16 + q * 4;
#pragma unroll
            for (int r = 0; r < 4; r++) {
                int row = rowb + r;
                if (row >= Mreal || col >= Nreal) continue;
                float x = acc[i][j][r] + bv;
                if (ACT == 1) x = 0.5f * x * (1.f + erff(x * 0.70710678118654752f));
                if (RES)      x += (float)res[(size_t)row * DM + col];
                if (HEAD) {
                    int bidx = row / NTOK, n = row - bidx * NTOK;
                    if (n < NVAR) {
                        float sc = stdv[bidx * NVAR + n], mm = mean[bidx * NVAR + n];
                        C[((size_t)bidx * PRED + col) * NVAR + n] = (CT)(x * sc + mm);
                    }
                } else {
                    C[(size_t)row * ldc + col] = (CT)x;
                }
            }
        }
    }
    if (HEAD && blockIdx.x == 0 && blockIdx.y == 0 && tid == 0)
        C[(size_t)BSZ * PRED * NVAR] = (CT)0.f;  // loss_reg = 0
}

// ---------------------------------------------------------------- conv + silu
// fwd (dir=0): xc[l] = silu(x[l-1]*w0 + x[l]*w1 + cb)
// rev (dir=1): xc[l] = silu(x[l+1]*w0 + x[l]*w1 + cb)
// xz chunk layout per token: [x_f(512) z_f(512) x_r(512) z_r(512)]
__global__ void conv_kernel(const bf* __restrict__ xz, const float* __restrict__ cw,
                            const float* __restrict__ cb, bf* __restrict__ xc, int Mc) {
    int id = blockIdx.x * 256 + threadIdx.x;   // 2*Mc*64 total
    int dir = id / (Mc * 64); int rem = id - dir * (Mc * 64);
    int token = rem >> 6; int ch0 = (rem & 63) * 8;
    int t = token % NTOK;
    const bf* xb = xz + (size_t)token * (4 * DM) + dir * (2 * DM) + ch0;
    bfrag xt = *(const bfrag*)xb;
    bfrag xn;
#pragma unroll
    for (int i = 0; i < 8; i++) xn[i] = (bf)0.f;
    int tn = dir ? t + 1 : t - 1;
    if ((unsigned)tn < (unsigned)NTOK)
        xn = *(const bfrag*)(xb + (dir ? (4 * DM) : -(4 * DM)));
    const float2* cwp = (const float2*)cw + ((size_t)dir * DM + ch0);
    const float*  cbp = cb + (size_t)dir * DM + ch0;
    bfrag ov;
#pragma unroll
    for (int jj = 0; jj < 8; jj++) {
        float2 w = cwp[jj];
        float x = (float)xn[jj] * w.x + (float)xt[jj] * w.y + cbp[jj];
        x = x / (1.f + __expf(-x));
        ov[jj] = (bf)x;
    }
    *(bfrag*)(xc + (size_t)dir * Mc * DM + (size_t)token * DM + ch0) = ov;
}

// ---------------------------------------------------------------- fused scan
// One lane = one channel d. The wave-uniform 64-float dbc row is staged
// through LDS (coalesced 256B load by lanes 0-15 -> ds_write_b128 ->
// broadcast ds_read_b128 by all lanes); dbc/x/z for token t+1 are
// prefetched during token t's compute. Single-wave block: DS ops are
// in-order within a wave, no barriers needed.
__global__ __launch_bounds__(64) void scan_kernel(
    const float* __restrict__ dbc, const bf* __restrict__ xc, const bf* __restrict__ xz,
    const float* __restrict__ Wdt, const float* __restrict__ bdt,
    const float* __restrict__ Alog, const float* __restrict__ Dp,
    bf* __restrict__ y, int Mc) {
    __shared__ __align__(16) float row[64];
    int lane = threadIdx.x;
    int dg = blockIdx.x, b = blockIdx.y, dir = blockIdx.z;
    int d = dg * 64 + lane;
    int dd = dir * DM + d;
    float wdt[32];
    {
        const f32x4* wp = (const f32x4*)(Wdt + (size_t)dd * DTR);
#pragma unroll
        for (int i = 0; i < 8; i++) {
            f32x4 v = wp[i];
            wdt[i * 4 + 0] = v[0]; wdt[i * 4 + 1] = v[1]; wdt[i * 4 + 2] = v[2]; wdt[i * 4 + 3] = v[3];
        }
    }
    float A2[16];
    {
        const f32x4* ap = (const f32x4*)(Alog + (size_t)dd * DS);
#pragma unroll
        for (int i = 0; i < 4; i++) {
            f32x4 v = ap[i];
#pragma unroll
            for (int jj = 0; jj < 4; jj++)
                A2[i * 4 + jj] = -__expf(v[jj]) * 1.4426950408889634f;  // *log2e
        }
    }
    float bdtv = bdt[dd];
    float Dd = Dp[dd];
    float h[16];
#pragma unroll
    for (int s = 0; s < 16; s++) h[s] = 0.f;

    const size_t xcb = (size_t)dir * Mc * DM;
    const size_t dbb = (size_t)dir * Mc;

    // prefetch token 0
    size_t tok = (size_t)b * NTOK + (dir ? (NTOK - 1) : 0);
    f32x4 gq;
    if (lane < 16) gq = ((const f32x4*)(dbc + (dbb + tok) * 64))[lane];
    bf xq = xc[xcb + tok * DM + d];
    bf zq = xz[tok * (4 * DM) + dir * (2 * DM) + DM + d];

    for (int t = 0; t < NTOK; t++) {
        size_t token = tok;
        // stage current row into LDS; capture current x/z
        if (lane < 16) ((f32x4*)row)[lane] = gq;
        float x = (float)xq;
        float zv = (float)zq;
        // prefetch token t+1 (independent of this iteration's compute)
        if (t + 1 < NTOK) {
            int ln = dir ? (NTOK - 2 - t) : (t + 1);
            tok = (size_t)b * NTOK + ln;
            if (lane < 16) gq = ((const f32x4*)(dbc + (dbb + tok) * 64))[lane];
            xq = xc[xcb + tok * DM + d];
            zq = xz[tok * (4 * DM) + dir * (2 * DM) + DM + d];
        }
        // dt = softplus(row[0:32] . wdt + bdt)   (broadcast LDS reads)
        const f32x4* rv = (const f32x4*)row;
        float a0 = bdtv, a1 = 0.f, a2 = 0.f, a3 = 0.f;
#pragma unroll
        for (int i = 0; i < 8; i++) {
            f32x4 qv = rv[i];
            a0 += qv[0] * wdt[i * 4 + 0];
            a1 += qv[1] * wdt[i * 4 + 1];
            a2 += qv[2] * wdt[i * 4 + 2];
            a3 += qv[3] * wdt[i * 4 + 3];
        }
        float dtl = (a0 + a1) + (a2 + a3);
        float dt = (dtl > 20.f) ? dtl : log1pf(__expf(dtl));
        float dtx = dt * x;
        float yv = 0.f;
#pragma unroll
        for (int i = 0; i < 4; i++) {
            f32x4 Bv = rv[8 + i];
            f32x4 Cv = rv[12 + i];
#pragma unroll
            for (int jj = 0; jj < 4; jj++) {
                int s = i * 4 + jj;
                float a = exp2f(dt * A2[s]);
                h[s] = a * h[s] + dtx * Bv[jj];
                yv += Cv[jj] * h[s];
            }
        }
        float sz = zv / (1.f + __expf(-zv));
        y[token * (2 * DM) + dir * DM + d] = (bf)((yv + Dd * x) * sz);
    }
}

// ---------------------------------------------------------------- LayerNorm
__global__ __launch_bounds__(256) void ln_kernel(const bf* X, bf* Y,
                                                 const float* __restrict__ g, const float* __restrict__ bb) {
    int token = blockIdx.x * 4 + (threadIdx.x >> 6);
    int lane = threadIdx.x & 63;
    bfrag xv = *(const bfrag*)(X + (size_t)token * DM + lane * 8);
    float xf[8]; float s = 0.f, sq = 0.f;
#pragma unroll
    for (int j = 0; j < 8; j++) { xf[j] = (float)xv[j]; s += xf[j]; sq += xf[j] * xf[j]; }
#pragma unroll
    for (int o = 1; o < 64; o <<= 1) { s += __shfl_xor(s, o); sq += __shfl_xor(sq, o); }
    float mu = s * (1.f / DM);
    float rs = rsqrtf(sq * (1.f / DM) - mu * mu + EPS);
    f32x4 g0 = ((const f32x4*)g)[lane * 2], g1 = ((const f32x4*)g)[lane * 2 + 1];
    f32x4 b0 = ((const f32x4*)bb)[lane * 2], b1 = ((const f32x4*)bb)[lane * 2 + 1];
    bfrag ov;
#pragma unroll
    for (int j = 0; j < 8; j++) {
        float gg = (j < 4) ? g0[j] : g1[j - 4];
        float bbv = (j < 4) ? b0[j] : b1[j - 4];
        ov[j] = (bf)((xf[j] - mu) * rs * gg + bbv);
    }
    *(bfrag*)(Y + (size_t)token * DM + lane * 8) = ov;
}

// ---------------------------------------------------------------- launch
extern "C" void kernel_launch(void* const* d_in, const int* in_sizes, int n_in,
                              void* d_out, int out_size, void* d_ws, size_t ws_size,
                              hipStream_t stream) {
    const float* x_enc = (const float*)d_in[0];
    const float* x_mark = (const float*)d_in[1];
    const float* W_emb = (const float*)d_in[4];
    const float* b_emb = (const float*)d_in[5];
    const float* mWin = (const float*)d_in[6];
    const float* mcw = (const float*)d_in[7];
    const float* mcb = (const float*)d_in[8];
    const float* mWx = (const float*)d_in[9];
    const float* mWdt = (const float*)d_in[10];
    const float* mbdt = (const float*)d_in[11];
    const float* mAlog = (const float*)d_in[12];
    const float* mD = (const float*)d_in[13];
    const float* mWout = (const float*)d_in[14];
    const float* W1w = (const float*)d_in[15];
    const float* b1w = (const float*)d_in[16];
    const float* W2w = (const float*)d_in[17];
    const float* b2w = (const float*)d_in[18];
    const float* ln1g = (const float*)d_in[19];
    const float* ln1b = (const float*)d_in[20];
    const float* ln2g = (const float*)d_in[21];
    const float* ln2b = (const float*)d_in[22];
    const float* lnfg = (const float*)d_in[23];
    const float* lnfb = (const float*)d_in[24];
    const float* headW = (const float*)d_in[25];
    const float* headb = (const float*)d_in[26];

    auto a256 = [](size_t x) { return (x + 255) & ~(size_t)255; };
    char* ws = (char*)d_ws;
    size_t off = 0;
    auto alloc = [&](size_t n) { size_t r = off; off += a256(n); return ws + r; };
    float* mean = (float*)alloc((size_t)BSZ * NVAR * 4);
    float* stdv = (float*)alloc((size_t)BSZ * NVAR * 4);
    bf* h  = (bf*)alloc((size_t)M * DM * 2);
    bf* t1 = (bf*)alloc((size_t)M * DM * 2);   // tok / hsum / ff
    bf* t2 = (bf*)alloc((size_t)M * DM * 2);   // h2
    // bf16-converted GEMM weights
    constexpr int nEmb = 512 * 512, nWin = NL * 2 * 1024 * 512, nWx = NL * 2 * 64 * 512,
                  nWout = NL * 2 * 512 * 512, nW1 = NL * DFF * DM, nW2 = NL * DM * DFF,
                  nHead = PRED * DM;
    bf* wEmb  = (bf*)alloc((size_t)nEmb * 2);
    bf* wWin  = (bf*)alloc((size_t)nWin * 2);
    bf* wWx   = (bf*)alloc((size_t)nWx * 2);
    bf* wWout = (bf*)alloc((size_t)nWout * 2);
    bf* wW1   = (bf*)alloc((size_t)nW1 * 2);
    bf* wW2   = (bf*)alloc((size_t)nW2 * 2);
    bf* wHead = (bf*)alloc((size_t)nHead * 2);
    size_t fixedEnd = off;

    // adaptive chunk size: CB batches per chunk
    // chunk bytes: xz(Mc*2048*2) + xc(2*Mc*512*2) + dbc(2*Mc*64*4) + y(Mc*1024*2)
    int CB = 1;
    {
        int cbs[6] = {32, 16, 8, 4, 2, 1};
        for (int i = 0; i < 6; i++) {
            size_t mc = (size_t)cbs[i] * NTOK;
            size_t chunkB = a256(mc * 4096) + a256(mc * 2048) + a256(mc * 512) + a256(mc * 2048);
            if (fixedEnd + chunkB <= ws_size) { CB = cbs[i]; break; }
        }
    }
    const size_t Mc = (size_t)CB * NTOK;
    size_t co = fixedEnd;
    bf* xzc = (bf*)(ws + co);    co += a256(Mc * 4096);
    bf* xcc = (bf*)(ws + co);    co += a256(Mc * 2048);
    float* dbcc = (float*)(ws + co); co += a256(Mc * 512);
    bf* ycc = (bf*)(ws + co);
    const int NC = BSZ / CB;
    const int MTc = (int)((Mc + 127) / 128);
    constexpr int MT = (M + 127) / 128;  // 217

    // weight conversion f32 -> bf16
    cvt_kernel<<<(nEmb / 4 + 255) / 256, 256, 0, stream>>>(W_emb, wEmb, nEmb / 4);
    cvt_kernel<<<(nWin / 4 + 255) / 256, 256, 0, stream>>>(mWin, wWin, nWin / 4);
    cvt_kernel<<<(nWx / 4 + 255) / 256, 256, 0, stream>>>(mWx, wWx, nWx / 4);
    cvt_kernel<<<(nWout / 4 + 255) / 256, 256, 0, stream>>>(mWout, wWout, nWout / 4);
    cvt_kernel<<<(nW1 / 4 + 255) / 256, 256, 0, stream>>>(W1w, wW1, nW1 / 4);
    cvt_kernel<<<(nW2 / 4 + 255) / 256, 256, 0, stream>>>(W2w, wW2, nW2 / 4);
    cvt_kernel<<<(nHead / 4 + 255) / 256, 256, 0, stream>>>(headW, wHead, nHead / 4);

    meanstd_kernel<<<dim3(4, BSZ), 256, 0, stream>>>(x_enc, mean, stdv);
    tok_kernel<<<dim3(28, 16, BSZ), dim3(32, 8), 0, stream>>>(x_enc, x_mark, mean, stdv, t1);
    // embedding: h = tok · W_emb^T + b_emb
    gemm_kernel<128, 0, true, false, false, bf><<<dim3(MT, 4), 256, 0, stream>>>(
        t1, nullptr, wEmb, nullptr, h, b_emb, nullptr,
        M, DM, SEQ, SEQ, SEQ, 0, DM, 0, 0, 0, nullptr, nullptr);

    for (int l = 0; l < NL; l++) {
        const bf* Winl = wWin + (size_t)l * 2 * 1024 * 512;
        const float* cwl = mcw + (size_t)l * 2 * DM * 2;
        const float* cbl = mcb + (size_t)l * 2 * DM;
        const bf* Wxl = wWx + (size_t)l * 2 * 64 * 512;
        const float* Wdtl = mWdt + (size_t)l * 2 * 512 * 32;
        const float* bdtl = mbdt + (size_t)l * 2 * DM;
        const float* Alogl = mAlog + (size_t)l * 2 * 512 * 16;
        const float* Dl = mD + (size_t)l * 2 * DM;
        const bf* Woutl = wWout + (size_t)l * 2 * 512 * 512;
        const bf* W1l = wW1 + (size_t)l * DFF * DM;
        const bf* W2l = wW2 + (size_t)l * DM * DFF;

        for (int c = 0; c < NC; c++) {
            size_t coff = (size_t)c * Mc;  // token offset
            // xz = h · [Win_f ; Win_r]^T   (N = 2048)
            gemm_kernel<128, 0, false, false, false, bf><<<dim3(MTc, 16), 256, 0, stream>>>(
                h + coff * DM, nullptr, Winl, nullptr, xzc, nullptr, nullptr,
                (int)Mc, 2048, 512, 512, 512, 0, 2048, 0, 0, 0, nullptr, nullptr);
            // conv + silu (both directions)
            conv_kernel<<<(int)(2 * Mc * 64 / 256), 256, 0, stream>>>(xzc, cwl, cbl, xcc, (int)Mc);
            // dbc = xc · Wx^T  (z-batched over dirs, N=64, f32 out)
            gemm_kernel<64, 0, false, false, false, float><<<dim3(MTc, 1, 2), 256, 0, stream>>>(
                xcc, nullptr, Wxl, nullptr, dbcc, nullptr, nullptr,
                (int)Mc, 64, 512, 512, 512, 0, 64,
                Mc * 512, (size_t)64 * 512, Mc * 64, nullptr, nullptr);
            // fused dt-proj + softplus + SSM scan + gate -> ycc
            scan_kernel<<<dim3(8, CB, 2), 64, 0, stream>>>(
                dbcc, xcc, xzc, Wdtl, bdtl, Alogl, Dl, ycc, (int)Mc);
            // hsum = h + y_f·Wout_f^T + y_r·Wout_r^T  (K=1024, split at 512)
            gemm_kernel<128, 0, false, true, false, bf><<<dim3(MTc, 4), 256, 0, stream>>>(
                ycc, ycc + 512, Woutl, Woutl + 512 * 512, t1 + coff * DM, nullptr, h + coff * DM,
                (int)Mc, DM, 1024, 1024, 512, 512, DM, 0, 0, 0, nullptr, nullptr);
        }
        ln_kernel<<<M / 4, 256, 0, stream>>>(t1, t2, ln1g + l * DM, ln1b + l * DM);
        // FFN
        gemm_kernel<128, 1, true, false, false, bf><<<dim3(MT, 4), 256, 0, stream>>>(
            t2, nullptr, W1l, nullptr, t1, b1w + l * DFF, nullptr,
            M, DFF, DM, DM, DM, 0, DFF, 0, 0, 0, nullptr, nullptr);
        gemm_kernel<128, 0, true, true, false, bf><<<dim3(MT, 4), 256, 0, stream>>>(
            t1, nullptr, W2l, nullptr, h, b2w + l * DM, t2,
            M, DM, DFF, DFF, DFF, 0, DM, 0, 0, 0, nullptr, nullptr);
        ln_kernel<<<M / 4, 256, 0, stream>>>(h, h, ln2g + l * DM, ln2b + l * DM);
    }

    ln_kernel<<<M / 4, 256, 0, stream>>>(h, t1, lnfg, lnfb);
    // head + de-normalize + scatter to (B, PRED, NVAR), plus loss scalar
    gemm_kernel<128, 0, true, false, true, float><<<dim3(MT, 1), 256, 0, stream>>>(
        t1, nullptr, wHead, nullptr, (float*)d_out, headb, nullptr,
        M, PRED, DM, DM, DM, 0, 1, 0, 0, 0, mean, stdv);
}

// Round 6
// 4167.642 us; speedup vs baseline: 2.8727x; 1.9108x over previous
//
#include <hip/hip_runtime.h>
#include <hip/hip_bf16.h>
#include <cmath>

typedef __bf16 bf;
typedef __bf16 bfrag __attribute__((ext_vector_type(8)));
typedef float  f32x4 __attribute__((ext_vector_type(4)));

constexpr int BSZ = 32, SEQ = 512, NVAR = 862, NMARK = 4, NTOK = 866;
constexpr int DM = 512, DS = 16, DTR = 32, DFF = 512, NL = 4, PRED = 96;
constexpr int M = BSZ * NTOK;              // 27712 tokens
constexpr float EPS = 1e-5f;
constexpr int NCH = 16, CL = 55;           // chunked scan: 16*55 = 880 >= 866
static_assert(NCH * CL >= NTOK, "chunks must cover sequence");

// ---------------------------------------------------------------- f32 -> bf16
__global__ void cvt_kernel(const float* __restrict__ src, bf* __restrict__ dst, int n4) {
    int i = blockIdx.x * 256 + threadIdx.x;
    if (i >= n4) return;
    f32x4 v = ((const f32x4*)src)[i];
    bf o[4];
    o[0] = (bf)v[0]; o[1] = (bf)v[1]; o[2] = (bf)v[2]; o[3] = (bf)v[3];
    *(uint2*)&dst[i * 4] = *(uint2*)o;
}

// ---------------------------------------------------------------- mean / std
__global__ void meanstd_kernel(const float* __restrict__ xe,
                               float* __restrict__ mean, float* __restrict__ stdv) {
    int v = blockIdx.x * 256 + threadIdx.x;
    int b = blockIdx.y;
    if (v >= NVAR) return;
    const float* p = xe + (size_t)b * SEQ * NVAR + v;
    float s = 0.f, sq = 0.f;
#pragma unroll 4
    for (int t = 0; t < SEQ; t++) {
        float x = p[(size_t)t * NVAR];
        s += x; sq += x * x;
    }
    float mu = s * (1.f / SEQ);
    float var = sq * (1.f / SEQ) - mu * mu;
    mean[b * NVAR + v] = mu;
    stdv[b * NVAR + v] = sqrtf(var + EPS);
}

// ------------------------------------------------- tok build (transpose+norm)
__global__ void tok_kernel(const float* __restrict__ xe, const float* __restrict__ xm,
                           const float* __restrict__ mean, const float* __restrict__ stdv,
                           bf* __restrict__ tok) {
    __shared__ float tile[32][33];
    int b = blockIdx.z;
    int v0 = blockIdx.x * 32, s0 = blockIdx.y * 32;
    int tx = threadIdx.x, ty = threadIdx.y;  // 32 x 8
    int v = v0 + tx;
    float mu = 0.f, rs = 0.f;
    if (v < NVAR) { mu = mean[b * NVAR + v]; rs = 1.f / stdv[b * NVAR + v]; }
#pragma unroll
    for (int j = 0; j < 4; j++) {
        int s = s0 + ty + j * 8;
        float val = 0.f;
        if (v < NVAR)       val = (xe[((size_t)b * SEQ + s) * NVAR + v] - mu) * rs;
        else if (v < NTOK)  val = xm[((size_t)b * SEQ + s) * NMARK + (v - NVAR)];
        tile[ty + j * 8][tx] = val;
    }
    __syncthreads();
#pragma unroll
    for (int j = 0; j < 4; j++) {
        int n = v0 + ty + j * 8;
        if (n < NTOK)
            tok[((size_t)b * NTOK + n) * SEQ + s0 + tx] = (bf)tile[tx][ty + j * 8];
    }
}

// ---------------------------------------------------------------- GEMM
// C[M,N] = A[M,K](bf16) * W[N,K]^T (bf16), f32 accumulate.
// ksplit: K-split for BOTH A (A0/A1) and W (W0/W1) at k=ksplit.
template <int BN, int ACT, bool BIAS, bool RES, bool HEAD, typename CT>
__global__ __launch_bounds__(256, 2) void gemm_kernel(
    const bf* __restrict__ A0, const bf* __restrict__ A1,
    const bf* __restrict__ W0, const bf* __restrict__ W1,
    CT* __restrict__ C, const float* __restrict__ bias, const bf* __restrict__ res,
    int Mreal, int Nreal, int K, int lda, int ldw, int ksplit, int ldc,
    size_t sAz, size_t sWz, size_t sCz,
    const float* __restrict__ mean, const float* __restrict__ stdv) {
    constexpr int BM = 128, BK = 64, SK = BK + 8;
    constexpr int NT = BN / 32;
    constexpr int ACH = BM * BK / 8 / 256;   // 4
    constexpr int BCH = BN * BK / 8 / 256;   // 4 or 2
    __shared__ __align__(16) bf Als[BM * SK];
    __shared__ __align__(16) bf Bls[BN * SK];

    int z = blockIdx.z;
    A0 += (size_t)z * sAz; W0 += (size_t)z * sWz; C += (size_t)z * sCz;
    int m0 = blockIdx.x * BM, n0 = blockIdx.y * BN;
    int tid = threadIdx.x, lane = tid & 63, wave = tid >> 6;
    int wm = wave >> 1, wn = wave & 1;
    int q = lane >> 4, ml = lane & 15;
    int rloc = tid >> 3, c8 = (tid & 7) * 8;

    f32x4 acc[4][NT];
#pragma unroll
    for (int i = 0; i < 4; i++)
#pragma unroll
        for (int j = 0; j < NT; j++) { acc[i][j][0] = 0.f; acc[i][j][1] = 0.f; acc[i][j][2] = 0.f; acc[i][j][3] = 0.f; }

    for (int kt = 0; kt < K; kt += BK) {
        int4 ra[ACH], rb[BCH];
        {
            const bf* abase = (ksplit && kt >= ksplit) ? (A1 + (kt - ksplit)) : (A0 + kt);
#pragma unroll
            for (int i = 0; i < ACH; i++) {
                int gm = m0 + rloc + i * 32;
                if (gm < Mreal) ra[i] = *(const int4*)(abase + (size_t)gm * lda + c8);
                else            ra[i] = int4{0, 0, 0, 0};
            }
        }
        {
            const bf* wsrc = (ksplit && kt >= ksplit) ? (W1 + (kt - ksplit)) : (W0 + kt);
#pragma unroll
            for (int i = 0; i < BCH; i++) {
                int r = rloc + i * 32;
                if (n0 + r < Nreal) rb[i] = *(const int4*)(wsrc + (size_t)(n0 + r) * ldw + c8);
                else                rb[i] = int4{0, 0, 0, 0};
            }
        }
        __syncthreads();
#pragma unroll
        for (int i = 0; i < ACH; i++) *(int4*)&Als[(rloc + i * 32) * SK + c8] = ra[i];
#pragma unroll
        for (int i = 0; i < BCH; i++) *(int4*)&Bls[(rloc + i * 32) * SK + c8] = rb[i];
        __syncthreads();
#pragma unroll
        for (int kk = 0; kk < BK; kk += 32) {
            bfrag af[4], bff[NT];
#pragma unroll
            for (int i = 0; i < 4; i++)
                af[i] = *(bfrag*)&Als[(wm * 64 + i * 16 + ml) * SK + kk + q * 8];
#pragma unroll
            for (int j = 0; j < NT; j++)
                bff[j] = *(bfrag*)&Bls[(wn * (BN / 2) + j * 16 + ml) * SK + kk + q * 8];
#pragma unroll
            for (int i = 0; i < 4; i++)
#pragma unroll
                for (int j = 0; j < NT; j++)
                    acc[i][j] = __builtin_amdgcn_mfma_f32_16x16x32_bf16(af[i], bff[j], acc[i][j], 0, 0, 0);
        }
        __syncthreads();
    }

#pragma unroll
    for (int j = 0; j < NT; j++) {
        int col = n0 + wn * (BN / 2) + j * 16 + ml;
        float bv = 0.f;
        if (BIAS && col < Nreal) bv = bias[col];
#pragma unroll
        for (int i = 0; i < 4; i++) {
            int rowb = m0 + wm * 64 + i * 16 + q * 4;
#pragma unroll
            for (int r = 0; r < 4; r++) {
                int row = rowb + r;
                if (row >= Mreal || col >= Nreal) continue;
                float x = acc[i][j][r] + bv;
                if (ACT == 1) x = 0.5f * x * (1.f + erff(x * 0.70710678118654752f));
                if (RES)      x += (float)res[(size_t)row * DM + col];
                if (HEAD) {
                    int bidx = row / NTOK, n = row - bidx * NTOK;
                    if (n < NVAR) {
                        float sc = stdv[bidx * NVAR + n], mm = mean[bidx * NVAR + n];
                        C[((size_t)bidx * PRED + col) * NVAR + n] = (CT)(x * sc + mm);
                    }
                } else {
                    C[(size_t)row * ldc + col] = (CT)x;
                }
            }
        }
    }
    if (HEAD && blockIdx.x == 0 && blockIdx.y == 0 && tid == 0)
        C[(size_t)BSZ * PRED * NVAR] = (CT)0.f;  // loss_reg = 0
}

// ---------------------------------------------------------------- conv + silu
__global__ void conv_kernel(const bf* __restrict__ xz, const float* __restrict__ cw,
                            const float* __restrict__ cb, bf* __restrict__ xc, int Mc) {
    int id = blockIdx.x * 256 + threadIdx.x;   // 2*Mc*64 total
    int dir = id / (Mc * 64); int rem = id - dir * (Mc * 64);
    int token = rem >> 6; int ch0 = (rem & 63) * 8;
    int t = token % NTOK;
    const bf* xb = xz + (size_t)token * (4 * DM) + dir * (2 * DM) + ch0;
    bfrag xt = *(const bfrag*)xb;
    bfrag xn;
#pragma unroll
    for (int i = 0; i < 8; i++) xn[i] = (bf)0.f;
    int tn = dir ? t + 1 : t - 1;
    if ((unsigned)tn < (unsigned)NTOK)
        xn = *(const bfrag*)(xb + (dir ? (4 * DM) : -(4 * DM)));
    const float2* cwp = (const float2*)cw + ((size_t)dir * DM + ch0);
    const float*  cbp = cb + (size_t)dir * DM + ch0;
    bfrag ov;
#pragma unroll
    for (int jj = 0; jj < 8; jj++) {
        float2 w = cwp[jj];
        float x = (float)xn[jj] * w.x + (float)xt[jj] * w.y + cbp[jj];
        x = x / (1.f + __expf(-x));
        ov[jj] = (bf)x;
    }
    *(bfrag*)(xc + (size_t)dir * Mc * DM + (size_t)token * DM + ch0) = ov;
}

// ---------------------------------------------------------------- chunked scan
// Diagonal linear recurrence h_s(t)=a_s(t)h_s(t-1)+b_s(t) split into NCH
// chunks for TLP. Phase A (FINAL=false): per-chunk local scan from h=0,
// stores final local state + decay product. Phase B (scan_fix): serial
// combine of NCH chunk summaries -> true initial state per chunk (in-place
// into hloc). Phase C (FINAL=true): re-run chunk with true init, emit y.
template <bool FINAL>
__global__ __launch_bounds__(64) void scan_chunk_kernel(
    const float* __restrict__ dbc, const bf* __restrict__ xc, const bf* __restrict__ xz,
    const float* __restrict__ Wdt, const float* __restrict__ bdt,
    const float* __restrict__ Alog, const float* __restrict__ Dp,
    float* __restrict__ hloc, float* __restrict__ aprod,
    bf* __restrict__ y, int Mc) {
    __shared__ __align__(16) float row[64];
    int lane = threadIdx.x;
    int dg = blockIdx.x, b = blockIdx.y;
    int zc = blockIdx.z; int dir = zc / NCH, c = zc - dir * NCH;
    int d = dg * 64 + lane;
    int dd = dir * DM + d;
    float wdt[32];
    {
        const f32x4* wp = (const f32x4*)(Wdt + (size_t)dd * DTR);
#pragma unroll
        for (int i = 0; i < 8; i++) {
            f32x4 v = wp[i];
            wdt[i * 4 + 0] = v[0]; wdt[i * 4 + 1] = v[1]; wdt[i * 4 + 2] = v[2]; wdt[i * 4 + 3] = v[3];
        }
    }
    float A2[16];
    {
        const f32x4* ap = (const f32x4*)(Alog + (size_t)dd * DS);
#pragma unroll
        for (int i = 0; i < 4; i++) {
            f32x4 v = ap[i];
#pragma unroll
            for (int jj = 0; jj < 4; jj++)
                A2[i * 4 + jj] = -__expf(v[jj]) * 1.4426950408889634f;  // *log2e
        }
    }
    float bdtv = bdt[dd];
    float Dd = FINAL ? Dp[dd] : 0.f;

    // per-(b,dir,dg,chunk,s) scratch index base
    const size_t sbase = (((((size_t)b * 2 + dir) * 8 + dg) * NCH + c) * 16) * 64 + lane;

    float h[16], ap[16];
#pragma unroll
    for (int s = 0; s < 16; s++) {
        if (FINAL) h[s] = hloc[sbase + (size_t)s * 64];
        else { h[s] = 0.f; ap[s] = 1.f; }
    }

    const size_t xcb = (size_t)dir * Mc * DM;
    const size_t dbb = (size_t)dir * Mc;
    const int t0 = c * CL;
    const int t1e = (t0 + CL < NTOK) ? t0 + CL : NTOK;

    // prefetch tau = t0
    size_t tok = (size_t)b * NTOK + (dir ? (NTOK - 1 - t0) : t0);
    f32x4 gq;
    if (lane < 16) gq = ((const f32x4*)(dbc + (dbb + tok) * 64))[lane];
    bf xq = xc[xcb + tok * DM + d];
    bf zq = (bf)0.f;
    if (FINAL) zq = xz[tok * (4 * DM) + dir * (2 * DM) + DM + d];

    for (int t = t0; t < t1e; t++) {
        size_t token = tok;
        if (lane < 16) ((f32x4*)row)[lane] = gq;
        float x = (float)xq;
        float zv = (float)zq;
        if (t + 1 < t1e) {
            int ln = dir ? (NTOK - 2 - t) : (t + 1);
            tok = (size_t)b * NTOK + ln;
            if (lane < 16) gq = ((const f32x4*)(dbc + (dbb + tok) * 64))[lane];
            xq = xc[xcb + tok * DM + d];
            if (FINAL) zq = xz[tok * (4 * DM) + dir * (2 * DM) + DM + d];
        }
        const f32x4* rv = (const f32x4*)row;
        float a0 = bdtv, a1 = 0.f, a2 = 0.f, a3 = 0.f;
#pragma unroll
        for (int i = 0; i < 8; i++) {
            f32x4 qv = rv[i];
            a0 += qv[0] * wdt[i * 4 + 0];
            a1 += qv[1] * wdt[i * 4 + 1];
            a2 += qv[2] * wdt[i * 4 + 2];
            a3 += qv[3] * wdt[i * 4 + 3];
        }
        float dtl = (a0 + a1) + (a2 + a3);
        float dt = (dtl > 20.f) ? dtl : log1pf(__expf(dtl));
        float dtx = dt * x;
        float yv = 0.f;
#pragma unroll
        for (int i = 0; i < 4; i++) {
            f32x4 Bv = rv[8 + i];
            f32x4 Cv = rv[12 + i];
#pragma unroll
            for (int jj = 0; jj < 4; jj++) {
                int s = i * 4 + jj;
                float a = exp2f(dt * A2[s]);
                h[s] = a * h[s] + dtx * Bv[jj];
                if (FINAL) yv += Cv[jj] * h[s];
                else       ap[s] *= a;
            }
        }
        if (FINAL) {
            float sz = zv / (1.f + __expf(-zv));
            y[token * (2 * DM) + dir * DM + d] = (bf)((yv + Dd * x) * sz);
        }
    }
    if (!FINAL) {
#pragma unroll
        for (int s = 0; s < 16; s++) {
            hloc[sbase + (size_t)s * 64] = h[s];
            aprod[sbase + (size_t)s * 64] = ap[s];
        }
    }
}

// Phase B: combine chunk summaries. One thread per (b,dir,dg,s,lane);
// serial over NCH chunks; writes true chunk-initial state into hloc.
__global__ void scan_fix_kernel(float* __restrict__ hloc, const float* __restrict__ aprod, int total) {
    int tid = blockIdx.x * 256 + threadIdx.x;
    if (tid >= total) return;
    int lane = tid & 63;
    int s = (tid >> 6) & 15;
    int g = tid >> 10;  // (b*2+dir)*8+dg
    size_t i0 = (((size_t)g * NCH) * 16 + s) * 64 + lane;
    float H = 0.f;
#pragma unroll
    for (int c = 0; c < NCH; c++) {
        size_t ix = i0 + (size_t)c * 1024;   // 16*64 per chunk
        float hl = hloc[ix];
        float ap = aprod[ix];
        hloc[ix] = H;
        H = hl + ap * H;
    }
}

// ---------------------------------------------------------------- LayerNorm
__global__ __launch_bounds__(256) void ln_kernel(const bf* X, bf* Y,
                                                 const float* __restrict__ g, const float* __restrict__ bb) {
    int token = blockIdx.x * 4 + (threadIdx.x >> 6);
    int lane = threadIdx.x & 63;
    bfrag xv = *(const bfrag*)(X + (size_t)token * DM + lane * 8);
    float xf[8]; float s = 0.f, sq = 0.f;
#pragma unroll
    for (int j = 0; j < 8; j++) { xf[j] = (float)xv[j]; s += xf[j]; sq += xf[j] * xf[j]; }
#pragma unroll
    for (int o = 1; o < 64; o <<= 1) { s += __shfl_xor(s, o); sq += __shfl_xor(sq, o); }
    float mu = s * (1.f / DM);
    float rs = rsqrtf(sq * (1.f / DM) - mu * mu + EPS);
    f32x4 g0 = ((const f32x4*)g)[lane * 2], g1 = ((const f32x4*)g)[lane * 2 + 1];
    f32x4 b0 = ((const f32x4*)bb)[lane * 2], b1 = ((const f32x4*)bb)[lane * 2 + 1];
    bfrag ov;
#pragma unroll
    for (int j = 0; j < 8; j++) {
        float gg = (j < 4) ? g0[j] : g1[j - 4];
        float bbv = (j < 4) ? b0[j] : b1[j - 4];
        ov[j] = (bf)((xf[j] - mu) * rs * gg + bbv);
    }
    *(bfrag*)(Y + (size_t)token * DM + lane * 8) = ov;
}

// ---------------------------------------------------------------- launch
extern "C" void kernel_launch(void* const* d_in, const int* in_sizes, int n_in,
                              void* d_out, int out_size, void* d_ws, size_t ws_size,
                              hipStream_t stream) {
    const float* x_enc = (const float*)d_in[0];
    const float* x_mark = (const float*)d_in[1];
    const float* W_emb = (const float*)d_in[4];
    const float* b_emb = (const float*)d_in[5];
    const float* mWin = (const float*)d_in[6];
    const float* mcw = (const float*)d_in[7];
    const float* mcb = (const float*)d_in[8];
    const float* mWx = (const float*)d_in[9];
    const float* mWdt = (const float*)d_in[10];
    const float* mbdt = (const float*)d_in[11];
    const float* mAlog = (const float*)d_in[12];
    const float* mD = (const float*)d_in[13];
    const float* mWout = (const float*)d_in[14];
    const float* W1w = (const float*)d_in[15];
    const float* b1w = (const float*)d_in[16];
    const float* W2w = (const float*)d_in[17];
    const float* b2w = (const float*)d_in[18];
    const float* ln1g = (const float*)d_in[19];
    const float* ln1b = (const float*)d_in[20];
    const float* ln2g = (const float*)d_in[21];
    const float* ln2b = (const float*)d_in[22];
    const float* lnfg = (const float*)d_in[23];
    const float* lnfb = (const float*)d_in[24];
    const float* headW = (const float*)d_in[25];
    const float* headb = (const float*)d_in[26];

    auto a256 = [](size_t x) { return (x + 255) & ~(size_t)255; };
    char* ws = (char*)d_ws;
    size_t off = 0;
    auto alloc = [&](size_t n) { size_t r = off; off += a256(n); return ws + r; };
    float* mean = (float*)alloc((size_t)BSZ * NVAR * 4);
    float* stdv = (float*)alloc((size_t)BSZ * NVAR * 4);
    bf* h  = (bf*)alloc((size_t)M * DM * 2);
    bf* t1 = (bf*)alloc((size_t)M * DM * 2);   // tok / hsum / ff
    bf* t2 = (bf*)alloc((size_t)M * DM * 2);   // h2
    // bf16-converted GEMM weights
    constexpr int nEmb = 512 * 512, nWin = NL * 2 * 1024 * 512, nWx = NL * 2 * 64 * 512,
                  nWout = NL * 2 * 512 * 512, nW1 = NL * DFF * DM, nW2 = NL * DM * DFF,
                  nHead = PRED * DM;
    bf* wEmb  = (bf*)alloc((size_t)nEmb * 2);
    bf* wWin  = (bf*)alloc((size_t)nWin * 2);
    bf* wWx   = (bf*)alloc((size_t)nWx * 2);
    bf* wWout = (bf*)alloc((size_t)nWout * 2);
    bf* wW1   = (bf*)alloc((size_t)nW1 * 2);
    bf* wW2   = (bf*)alloc((size_t)nW2 * 2);
    bf* wHead = (bf*)alloc((size_t)nHead * 2);
    size_t fixedEnd = off;

    // adaptive chunk size: CB batches per chunk
    // chunk bytes: xz + xc + dbc + y + scan scratch (hloc + aprod)
    auto scanScr = [&](size_t cb) { return cb * 2 * 8 * (size_t)NCH * 16 * 64 * 4; };
    int CB = 1;
    {
        int cbs[6] = {32, 16, 8, 4, 2, 1};
        for (int i = 0; i < 6; i++) {
            size_t mc = (size_t)cbs[i] * NTOK;
            size_t chunkB = a256(mc * 4096) + a256(mc * 2048) + a256(mc * 512) + a256(mc * 2048)
                          + 2 * a256(scanScr(cbs[i]));
            if (fixedEnd + chunkB <= ws_size) { CB = cbs[i]; break; }
        }
    }
    const size_t Mc = (size_t)CB * NTOK;
    size_t co = fixedEnd;
    bf* xzc = (bf*)(ws + co);    co += a256(Mc * 4096);
    bf* xcc = (bf*)(ws + co);    co += a256(Mc * 2048);
    float* dbcc = (float*)(ws + co); co += a256(Mc * 512);
    bf* ycc = (bf*)(ws + co);    co += a256(Mc * 2048);
    float* hloc = (float*)(ws + co); co += a256(scanScr(CB));
    float* aprod = (float*)(ws + co);
    const int NC = BSZ / CB;
    const int MTc = (int)((Mc + 127) / 128);
    constexpr int MT = (M + 127) / 128;  // 217
    const int fixTotal = CB * 2 * 8 * 16 * 64;

    // weight conversion f32 -> bf16
    cvt_kernel<<<(nEmb / 4 + 255) / 256, 256, 0, stream>>>(W_emb, wEmb, nEmb / 4);
    cvt_kernel<<<(nWin / 4 + 255) / 256, 256, 0, stream>>>(mWin, wWin, nWin / 4);
    cvt_kernel<<<(nWx / 4 + 255) / 256, 256, 0, stream>>>(mWx, wWx, nWx / 4);
    cvt_kernel<<<(nWout / 4 + 255) / 256, 256, 0, stream>>>(mWout, wWout, nWout / 4);
    cvt_kernel<<<(nW1 / 4 + 255) / 256, 256, 0, stream>>>(W1w, wW1, nW1 / 4);
    cvt_kernel<<<(nW2 / 4 + 255) / 256, 256, 0, stream>>>(W2w, wW2, nW2 / 4);
    cvt_kernel<<<(nHead / 4 + 255) / 256, 256, 0, stream>>>(headW, wHead, nHead / 4);

    meanstd_kernel<<<dim3(4, BSZ), 256, 0, stream>>>(x_enc, mean, stdv);
    tok_kernel<<<dim3(28, 16, BSZ), dim3(32, 8), 0, stream>>>(x_enc, x_mark, mean, stdv, t1);
    // embedding: h = tok · W_emb^T + b_emb
    gemm_kernel<128, 0, true, false, false, bf><<<dim3(MT, 4), 256, 0, stream>>>(
        t1, nullptr, wEmb, nullptr, h, b_emb, nullptr,
        M, DM, SEQ, SEQ, SEQ, 0, DM, 0, 0, 0, nullptr, nullptr);

    for (int l = 0; l < NL; l++) {
        const bf* Winl = wWin + (size_t)l * 2 * 1024 * 512;
        const float* cwl = mcw + (size_t)l * 2 * DM * 2;
        const float* cbl = mcb + (size_t)l * 2 * DM;
        const bf* Wxl = wWx + (size_t)l * 2 * 64 * 512;
        const float* Wdtl = mWdt + (size_t)l * 2 * 512 * 32;
        const float* bdtl = mbdt + (size_t)l * 2 * DM;
        const float* Alogl = mAlog + (size_t)l * 2 * 512 * 16;
        const float* Dl = mD + (size_t)l * 2 * DM;
        const bf* Woutl = wWout + (size_t)l * 2 * 512 * 512;
        const bf* W1l = wW1 + (size_t)l * DFF * DM;
        const bf* W2l = wW2 + (size_t)l * DM * DFF;

        for (int c = 0; c < NC; c++) {
            size_t coff = (size_t)c * Mc;  // token offset
            // xz = h · [Win_f ; Win_r]^T   (N = 2048)
            gemm_kernel<128, 0, false, false, false, bf><<<dim3(MTc, 16), 256, 0, stream>>>(
                h + coff * DM, nullptr, Winl, nullptr, xzc, nullptr, nullptr,
                (int)Mc, 2048, 512, 512, 512, 0, 2048, 0, 0, 0, nullptr, nullptr);
            // conv + silu (both directions)
            conv_kernel<<<(int)(2 * Mc * 64 / 256), 256, 0, stream>>>(xzc, cwl, cbl, xcc, (int)Mc);
            // dbc = xc · Wx^T  (z-batched over dirs, N=64, f32 out)
            gemm_kernel<64, 0, false, false, false, float><<<dim3(MTc, 1, 2), 256, 0, stream>>>(
                xcc, nullptr, Wxl, nullptr, dbcc, nullptr, nullptr,
                (int)Mc, 64, 512, 512, 512, 0, 64,
                Mc * 512, (size_t)64 * 512, Mc * 64, nullptr, nullptr);
            // chunked scan: A (local) -> B (fix) -> C (final, writes y)
            scan_chunk_kernel<false><<<dim3(8, CB, 2 * NCH), 64, 0, stream>>>(
                dbcc, xcc, xzc, Wdtl, bdtl, Alogl, Dl, hloc, aprod, ycc, (int)Mc);
            scan_fix_kernel<<<(fixTotal + 255) / 256, 256, 0, stream>>>(hloc, aprod, fixTotal);
            scan_chunk_kernel<true><<<dim3(8, CB, 2 * NCH), 64, 0, stream>>>(
                dbcc, xcc, xzc, Wdtl, bdtl, Alogl, Dl, hloc, aprod, ycc, (int)Mc);
            // hsum = h + y_f·Wout_f^T + y_r·Wout_r^T  (K=1024, split at 512)
            gemm_kernel<128, 0, false, true, false, bf><<<dim3(MTc, 4), 256, 0, stream>>>(
                ycc, ycc + 512, Woutl, Woutl + 512 * 512, t1 + coff * DM, nullptr, h + coff * DM,
                (int)Mc, DM, 1024, 1024, 512, 512, DM, 0, 0, 0, nullptr, nullptr);
        }
        ln_kernel<<<M / 4, 256, 0, stream>>>(t1, t2, ln1g + l * DM, ln1b + l * DM);
        // FFN
        gemm_kernel<128, 1, true, false, false, bf><<<dim3(MT, 4), 256, 0, stream>>>(
            t2, nullptr, W1l, nullptr, t1, b1w + l * DFF, nullptr,
            M, DFF, DM, DM, DM, 0, DFF, 0, 0, 0, nullptr, nullptr);
        gemm_kernel<128, 0, true, true, false, bf><<<dim3(MT, 4), 256, 0, stream>>>(
            t1, nullptr, W2l, nullptr, h, b2w + l * DM, t2,
            M, DM, DFF, DFF, DFF, 0, DM, 0, 0, 0, nullptr, nullptr);
        ln_kernel<<<M / 4, 256, 0, stream>>>(h, h, ln2g + l * DM, ln2b + l * DM);
    }

    ln_kernel<<<M / 4, 256, 0, stream>>>(h, t1, lnfg, lnfb);
    // head + de-normalize + scatter to (B, PRED, NVAR), plus loss scalar
    gemm_kernel<128, 0, true, false, true, float><<<dim3(MT, 1), 256, 0, stream>>>(
        t1, nullptr, wHead, nullptr, (float*)d_out, headb, nullptr,
        M, PRED, DM, DM, DM, 0, 1, 0, 0, 0, mean, stdv);
}

// Round 7
// 3655.442 us; speedup vs baseline: 3.2752x; 1.1401x over previous
//
#include <hip/hip_runtime.h>
#include <hip/hip_bf16.h>
#include <cmath>

typedef __bf16 bf;
typedef __bf16 bfrag __attribute__((ext_vector_type(8)));
typedef float  f32x4 __attribute__((ext_vector_type(4)));

constexpr int BSZ = 32, SEQ = 512, NVAR = 862, NMARK = 4, NTOK = 866;
constexpr int DM = 512, DS = 16, DTR = 32, DFF = 512, NL = 4, PRED = 96;
constexpr int M = BSZ * NTOK;              // 27712 tokens
constexpr float EPS = 1e-5f;
constexpr int NCH = 32, CL = 28;           // chunked scan: 32*28 = 896 >= 866
static_assert(NCH * CL >= NTOK, "chunks must cover sequence");

// ---------------------------------------------------------------- f32 -> bf16
__global__ void cvt_kernel(const float* __restrict__ src, bf* __restrict__ dst, int n4) {
    int i = blockIdx.x * 256 + threadIdx.x;
    if (i >= n4) return;
    f32x4 v = ((const f32x4*)src)[i];
    bf o[4];
    o[0] = (bf)v[0]; o[1] = (bf)v[1]; o[2] = (bf)v[2]; o[3] = (bf)v[3];
    *(uint2*)&dst[i * 4] = *(uint2*)o;
}

// ------------------------------------------- fold Wdt(512x32)·Wx32(32x512)
// out[l][dir][d][k] = sum_r Wdt[l][dir][d][r] * Wx[l][dir][r][k]   (bf16 out)
__global__ void fold_kernel(const float* __restrict__ Wdt, const float* __restrict__ Wx,
                            bf* __restrict__ out) {
    int idx = blockIdx.x * 256 + threadIdx.x;     // NL*2*512*512 total
    int k = idx & 511, d = (idx >> 9) & 511, ld = idx >> 18;
    const float* wd = Wdt + (size_t)(ld * 512 + d) * 32;
    const float* wx = Wx + (size_t)ld * 64 * 512 + k;
    float s = 0.f;
#pragma unroll 8
    for (int r = 0; r < 32; r++) s += wd[r] * wx[(size_t)r * 512];
    out[(size_t)(ld * 512 + d) * 512 + k] = (bf)s;
}

// ---------------------------------------------------------------- mean / std
__global__ void meanstd_kernel(const float* __restrict__ xe,
                               float* __restrict__ mean, float* __restrict__ stdv) {
    int v = blockIdx.x * 256 + threadIdx.x;
    int b = blockIdx.y;
    if (v >= NVAR) return;
    const float* p = xe + (size_t)b * SEQ * NVAR + v;
    float s = 0.f, sq = 0.f;
#pragma unroll 4
    for (int t = 0; t < SEQ; t++) {
        float x = p[(size_t)t * NVAR];
        s += x; sq += x * x;
    }
    float mu = s * (1.f / SEQ);
    float var = sq * (1.f / SEQ) - mu * mu;
    mean[b * NVAR + v] = mu;
    stdv[b * NVAR + v] = sqrtf(var + EPS);
}

// ------------------------------------------------- tok build (transpose+norm)
__global__ void tok_kernel(const float* __restrict__ xe, const float* __restrict__ xm,
                           const float* __restrict__ mean, const float* __restrict__ stdv,
                           bf* __restrict__ tok) {
    __shared__ float tile[32][33];
    int b = blockIdx.z;
    int v0 = blockIdx.x * 32, s0 = blockIdx.y * 32;
    int tx = threadIdx.x, ty = threadIdx.y;  // 32 x 8
    int v = v0 + tx;
    float mu = 0.f, rs = 0.f;
    if (v < NVAR) { mu = mean[b * NVAR + v]; rs = 1.f / stdv[b * NVAR + v]; }
#pragma unroll
    for (int j = 0; j < 4; j++) {
        int s = s0 + ty + j * 8;
        float val = 0.f;
        if (v < NVAR)       val = (xe[((size_t)b * SEQ + s) * NVAR + v] - mu) * rs;
        else if (v < NTOK)  val = xm[((size_t)b * SEQ + s) * NMARK + (v - NVAR)];
        tile[ty + j * 8][tx] = val;
    }
    __syncthreads();
#pragma unroll
    for (int j = 0; j < 4; j++) {
        int n = v0 + ty + j * 8;
        if (n < NTOK)
            tok[((size_t)b * NTOK + n) * SEQ + s0 + tx] = (bf)tile[tx][ty + j * 8];
    }
}

// ---------------------------------------------------------------- GEMM
// C[M,N] = A[M,K](bf16) * W[N,K]^T (bf16), f32 accumulate.
// ACT: 0 none, 1 exact-gelu, 2 softplus.
// ksplit: K-split for BOTH A (A0/A1) and W (W0/W1) at k=ksplit.
template <int BN, int ACT, bool BIAS, bool RES, bool HEAD, typename CT>
__global__ __launch_bounds__(256, 2) void gemm_kernel(
    const bf* __restrict__ A0, const bf* __restrict__ A1,
    const bf* __restrict__ W0, const bf* __restrict__ W1,
    CT* __restrict__ C, const float* __restrict__ bias, const bf* __restrict__ res,
    int Mreal, int Nreal, int K, int lda, int ldw, int ksplit, int ldc,
    size_t sAz, size_t sWz, size_t sCz, size_t sBiasz,
    const float* __restrict__ mean, const float* __restrict__ stdv) {
    constexpr int BM = 128, BK = 64, SK = BK + 8;
    constexpr int NT = BN / 32;
    constexpr int ACH = BM * BK / 8 / 256;   // 4
    constexpr int BCH = BN * BK / 8 / 256;   // 4 or 2
    __shared__ __align__(16) bf Als[BM * SK];
    __shared__ __align__(16) bf Bls[BN * SK];

    int z = blockIdx.z;
    A0 += (size_t)z * sAz; W0 += (size_t)z * sWz; C += (size_t)z * sCz;
    if (BIAS) bias += (size_t)z * sBiasz;
    int m0 = blockIdx.x * BM, n0 = blockIdx.y * BN;
    int tid = threadIdx.x, lane = tid & 63, wave = tid >> 6;
    int wm = wave >> 1, wn = wave & 1;
    int q = lane >> 4, ml = lane & 15;
    int rloc = tid >> 3, c8 = (tid & 7) * 8;

    f32x4 acc[4][NT];
#pragma unroll
    for (int i = 0; i < 4; i++)
#pragma unroll
        for (int j = 0; j < NT; j++) { acc[i][j][0] = 0.f; acc[i][j][1] = 0.f; acc[i][j][2] = 0.f; acc[i][j][3] = 0.f; }

    for (int kt = 0; kt < K; kt += BK) {
        int4 ra[ACH], rb[BCH];
        {
            const bf* abase = (ksplit && kt >= ksplit) ? (A1 + (kt - ksplit)) : (A0 + kt);
#pragma unroll
            for (int i = 0; i < ACH; i++) {
                int gm = m0 + rloc + i * 32;
                if (gm < Mreal) ra[i] = *(const int4*)(abase + (size_t)gm * lda + c8);
                else            ra[i] = int4{0, 0, 0, 0};
            }
        }
        {
            const bf* wsrc = (ksplit && kt >= ksplit) ? (W1 + (kt - ksplit)) : (W0 + kt);
#pragma unroll
            for (int i = 0; i < BCH; i++) {
                int r = rloc + i * 32;
                if (n0 + r < Nreal) rb[i] = *(const int4*)(wsrc + (size_t)(n0 + r) * ldw + c8);
                else                rb[i] = int4{0, 0, 0, 0};
            }
        }
        __syncthreads();
#pragma unroll
        for (int i = 0; i < ACH; i++) *(int4*)&Als[(rloc + i * 32) * SK + c8] = ra[i];
#pragma unroll
        for (int i = 0; i < BCH; i++) *(int4*)&Bls[(rloc + i * 32) * SK + c8] = rb[i];
        __syncthreads();
#pragma unroll
        for (int kk = 0; kk < BK; kk += 32) {
            bfrag af[4], bff[NT];
#pragma unroll
            for (int i = 0; i < 4; i++)
                af[i] = *(bfrag*)&Als[(wm * 64 + i * 16 + ml) * SK + kk + q * 8];
#pragma unroll
            for (int j = 0; j < NT; j++)
                bff[j] = *(bfrag*)&Bls[(wn * (BN / 2) + j * 16 + ml) * SK + kk + q * 8];
#pragma unroll
            for (int i = 0; i < 4; i++)
#pragma unroll
                for (int j = 0; j < NT; j++)
                    acc[i][j] = __builtin_amdgcn_mfma_f32_16x16x32_bf16(af[i], bff[j], acc[i][j], 0, 0, 0);
        }
        __syncthreads();
    }

#pragma unroll
    for (int j = 0; j < NT; j++) {
        int col = n0 + wn * (BN / 2) + j * 16 + ml;
        float bv = 0.f;
        if (BIAS && col < Nreal) bv = bias[col];
#pragma unroll
        for (int i = 0; i < 4; i++) {
            int rowb = m0 + wm * 64 + i * 16 + q * 4;
#pragma unroll
            for (int r = 0; r < 4; r++) {
                int row = rowb + r;
                if (row >= Mreal || col >= Nreal) continue;
                float x = acc[i][j][r] + bv;
                if (ACT == 1) x = 0.5f * x * (1.f + erff(x * 0.70710678118654752f));
                if (ACT == 2) x = (x > 20.f) ? x : __logf(1.f + __expf(x));
                if (RES)      x += (float)res[(size_t)row * DM + col];
                if (HEAD) {
                    int bidx = row / NTOK, n = row - bidx * NTOK;
                    if (n < NVAR) {
                        float sc = stdv[bidx * NVAR + n], mm = mean[bidx * NVAR + n];
                        C[((size_t)bidx * PRED + col) * NVAR + n] = (CT)(x * sc + mm);
                    }
                } else {
                    C[(size_t)row * ldc + col] = (CT)x;
                }
            }
        }
    }
    if (HEAD && blockIdx.x == 0 && blockIdx.y == 0 && tid == 0)
        C[(size_t)BSZ * PRED * NVAR] = (CT)0.f;  // loss_reg = 0
}

// ---------------------------------------------------------------- conv + silu
__global__ void conv_kernel(const bf* __restrict__ xz, const float* __restrict__ cw,
                            const float* __restrict__ cb, bf* __restrict__ xc, int Mc) {
    int id = blockIdx.x * 256 + threadIdx.x;   // 2*Mc*64 total
    int dir = id / (Mc * 64); int rem = id - dir * (Mc * 64);
    int token = rem >> 6; int ch0 = (rem & 63) * 8;
    int t = token % NTOK;
    const bf* xb = xz + (size_t)token * (4 * DM) + dir * (2 * DM) + ch0;
    bfrag xt = *(const bfrag*)xb;
    bfrag xn;
#pragma unroll
    for (int i = 0; i < 8; i++) xn[i] = (bf)0.f;
    int tn = dir ? t + 1 : t - 1;
    if ((unsigned)tn < (unsigned)NTOK)
        xn = *(const bfrag*)(xb + (dir ? (4 * DM) : -(4 * DM)));
    const float2* cwp = (const float2*)cw + ((size_t)dir * DM + ch0);
    const float*  cbp = cb + (size_t)dir * DM + ch0;
    bfrag ov;
#pragma unroll
    for (int jj = 0; jj < 8; jj++) {
        float2 w = cwp[jj];
        float x = (float)xn[jj] * w.x + (float)xt[jj] * w.y + cbp[jj];
        x = x / (1.f + __expf(-x));
        ov[jj] = (bf)x;
    }
    *(bfrag*)(xc + (size_t)dir * Mc * DM + (size_t)token * DM + ch0) = ov;
}

// ---------------------------------------------------------------- chunked scan
// dt precomputed by GEMM (softplus included). Per token: load dt (f32/lane),
// stage 32-float B|C row via LDS broadcast, 16-state recurrence. Decay
// factors exp2(dt*A2_s): fast path uses A2_s = (s+1)*A2_0 (ballot-verified)
// -> one exp2 + 15 muls. Phase A accumulates sum(dt); aprod = exp2(A2_s*sum).
template <bool FINAL>
__global__ __launch_bounds__(64) void scan_chunk_kernel(
    const float* __restrict__ dtc, const float* __restrict__ dbc,
    const bf* __restrict__ xc, const bf* __restrict__ xz,
    const float* __restrict__ Alog, const float* __restrict__ Dp,
    float* __restrict__ hloc, float* __restrict__ aprod,
    bf* __restrict__ y, int Mc) {
    __shared__ __align__(16) float row[32];
    int lane = threadIdx.x;
    int dg = blockIdx.x, b = blockIdx.y;
    int zc = blockIdx.z; int dir = zc / NCH, c = zc - dir * NCH;
    int d = dg * 64 + lane;
    int dd = dir * DM + d;
    float A2[16];
    {
        const f32x4* ap = (const f32x4*)(Alog + (size_t)dd * DS);
#pragma unroll
        for (int i = 0; i < 4; i++) {
            f32x4 v = ap[i];
#pragma unroll
            for (int jj = 0; jj < 4; jj++)
                A2[i * 4 + jj] = -__expf(v[jj]) * 1.4426950408889634f;  // *log2e
        }
    }
    float A20 = A2[0];
    bool lc = true;
#pragma unroll
    for (int s = 1; s < 16; s++)
        lc = lc && (fabsf(A2[s] - (s + 1) * A20) <= 1e-4f * fabsf(A2[s]));
    bool fast = (__ballot(lc) == ~0ull);
    float Dd = FINAL ? Dp[dd] : 0.f;

    const size_t sbase = (((((size_t)b * 2 + dir) * 8 + dg) * NCH + c) * 16) * 64 + lane;
    float h[16];
#pragma unroll
    for (int s = 0; s < 16; s++) h[s] = FINAL ? hloc[sbase + (size_t)s * 64] : 0.f;
    float dtsum = 0.f;

    const int t0 = c * CL;
    const int t1e = (t0 + CL < NTOK) ? t0 + CL : NTOK;
    const long step = dir ? -1 : 1;

    const float* dtp = nullptr; const float* bcp = nullptr;
    const bf* xcp = nullptr; const bf* xzp = nullptr; bf* yp = nullptr;
    float dtq = 0.f; f32x4 gq = {0.f, 0.f, 0.f, 0.f}; bf xq = (bf)0.f, zq = (bf)0.f;
    if (t0 < t1e) {
        long tok0 = (long)b * NTOK + (dir ? (NTOK - 1 - t0) : t0);
        dtp = dtc + (size_t)dir * Mc * 512 + (size_t)tok0 * 512 + d;
        bcp = dbc + ((size_t)dir * Mc + (size_t)tok0) * 32;
        xcp = xc + (size_t)dir * Mc * 512 + (size_t)tok0 * 512 + d;
        dtq = *dtp;
        if (lane < 8) gq = ((const f32x4*)bcp)[lane];
        xq = *xcp;
        if (FINAL) {
            xzp = xz + (size_t)tok0 * 2048 + dir * 1024 + 512 + d;
            yp  = y  + (size_t)tok0 * 1024 + dir * 512 + d;
            zq = *xzp;
        }
    }
    const long sdt = step * 512, sbc = step * 32, sxc = step * 512;
    const long sxz = step * 2048, sy = step * 1024;

    for (int t = t0; t < t1e; t++) {
        if (lane < 8) ((f32x4*)row)[lane] = gq;
        float dt = dtq;
        float x = (float)xq;
        float zv = (float)zq;
        bf* ypc = yp;
        if (t + 1 < t1e) {
            dtp += sdt; bcp += sbc; xcp += sxc;
            dtq = *dtp;
            if (lane < 8) gq = ((const f32x4*)bcp)[lane];
            xq = *xcp;
            if (FINAL) { xzp += sxz; zq = *xzp; yp += sy; }
        }
        const f32x4* rv = (const f32x4*)row;
        float dtx = dt * x;
        dtsum += dt;
        float yv = 0.f;
        if (fast) {
            float r = exp2f(dt * A20);
            float rp = 1.f;
#pragma unroll
            for (int i = 0; i < 4; i++) {
                f32x4 Bv = rv[i];
                f32x4 Cv = rv[4 + i];
#pragma unroll
                for (int jj = 0; jj < 4; jj++) {
                    int s = i * 4 + jj;
                    rp *= r;
                    h[s] = rp * h[s] + dtx * Bv[jj];
                    if (FINAL) yv += Cv[jj] * h[s];
                }
            }
        } else {
#pragma unroll
            for (int i = 0; i < 4; i++) {
                f32x4 Bv = rv[i];
                f32x4 Cv = rv[4 + i];
#pragma unroll
                for (int jj = 0; jj < 4; jj++) {
                    int s = i * 4 + jj;
                    float a = exp2f(dt * A2[s]);
                    h[s] = a * h[s] + dtx * Bv[jj];
                    if (FINAL) yv += Cv[jj] * h[s];
                }
            }
        }
        if (FINAL) {
            float sz = zv / (1.f + __expf(-zv));
            *ypc = (bf)((yv + Dd * x) * sz);
        }
    }
    if (!FINAL) {
#pragma unroll
        for (int s = 0; s < 16; s++) {
            hloc[sbase + (size_t)s * 64] = h[s];
            aprod[sbase + (size_t)s * 64] = exp2f(dtsum * A2[s]);
        }
    }
}

// Phase B: combine chunk summaries (serial over NCH chunks per group).
__global__ void scan_fix_kernel(float* __restrict__ hloc, const float* __restrict__ aprod, int total) {
    int tid = blockIdx.x * 256 + threadIdx.x;
    if (tid >= total) return;
    int lane = tid & 63;
    int s = (tid >> 6) & 15;
    int g = tid >> 10;  // (b*2+dir)*8+dg
    size_t i0 = (((size_t)g * NCH) * 16 + s) * 64 + lane;
    float H = 0.f;
#pragma unroll
    for (int c = 0; c < NCH; c++) {
        size_t ix = i0 + (size_t)c * 1024;   // 16*64 per chunk
        float hl = hloc[ix];
        float ap = aprod[ix];
        hloc[ix] = H;
        H = hl + ap * H;
    }
}

// ---------------------------------------------------------------- LayerNorm
__global__ __launch_bounds__(256) void ln_kernel(const bf* X, bf* Y,
                                                 const float* __restrict__ g, const float* __restrict__ bb) {
    int token = blockIdx.x * 4 + (threadIdx.x >> 6);
    int lane = threadIdx.x & 63;
    bfrag xv = *(const bfrag*)(X + (size_t)token * DM + lane * 8);
    float xf[8]; float s = 0.f, sq = 0.f;
#pragma unroll
    for (int j = 0; j < 8; j++) { xf[j] = (float)xv[j]; s += xf[j]; sq += xf[j] * xf[j]; }
#pragma unroll
    for (int o = 1; o < 64; o <<= 1) { s += __shfl_xor(s, o); sq += __shfl_xor(sq, o); }
    float mu = s * (1.f / DM);
    float rs = rsqrtf(sq * (1.f / DM) - mu * mu + EPS);
    f32x4 g0 = ((const f32x4*)g)[lane * 2], g1 = ((const f32x4*)g)[lane * 2 + 1];
    f32x4 b0 = ((const f32x4*)bb)[lane * 2], b1 = ((const f32x4*)bb)[lane * 2 + 1];
    bfrag ov;
#pragma unroll
    for (int j = 0; j < 8; j++) {
        float gg = (j < 4) ? g0[j] : g1[j - 4];
        float bbv = (j < 4) ? b0[j] : b1[j - 4];
        ov[j] = (bf)((xf[j] - mu) * rs * gg + bbv);
    }
    *(bfrag*)(Y + (size_t)token * DM + lane * 8) = ov;
}

// ---------------------------------------------------------------- launch
extern "C" void kernel_launch(void* const* d_in, const int* in_sizes, int n_in,
                              void* d_out, int out_size, void* d_ws, size_t ws_size,
                              hipStream_t stream) {
    const float* x_enc = (const float*)d_in[0];
    const float* x_mark = (const float*)d_in[1];
    const float* W_emb = (const float*)d_in[4];
    const float* b_emb = (const float*)d_in[5];
    const float* mWin = (const float*)d_in[6];
    const float* mcw = (const float*)d_in[7];
    const float* mcb = (const float*)d_in[8];
    const float* mWx = (const float*)d_in[9];
    const float* mWdt = (const float*)d_in[10];
    const float* mbdt = (const float*)d_in[11];
    const float* mAlog = (const float*)d_in[12];
    const float* mD = (const float*)d_in[13];
    const float* mWout = (const float*)d_in[14];
    const float* W1w = (const float*)d_in[15];
    const float* b1w = (const float*)d_in[16];
    const float* W2w = (const float*)d_in[17];
    const float* b2w = (const float*)d_in[18];
    const float* ln1g = (const float*)d_in[19];
    const float* ln1b = (const float*)d_in[20];
    const float* ln2g = (const float*)d_in[21];
    const float* ln2b = (const float*)d_in[22];
    const float* lnfg = (const float*)d_in[23];
    const float* lnfb = (const float*)d_in[24];
    const float* headW = (const float*)d_in[25];
    const float* headb = (const float*)d_in[26];

    auto a256 = [](size_t x) { return (x + 255) & ~(size_t)255; };
    char* ws = (char*)d_ws;
    size_t off = 0;
    auto alloc = [&](size_t n) { size_t r = off; off += a256(n); return ws + r; };
    float* mean = (float*)alloc((size_t)BSZ * NVAR * 4);
    float* stdv = (float*)alloc((size_t)BSZ * NVAR * 4);
    bf* h  = (bf*)alloc((size_t)M * DM * 2);
    bf* t1 = (bf*)alloc((size_t)M * DM * 2);   // tok / hsum / ff
    bf* t2 = (bf*)alloc((size_t)M * DM * 2);   // h2
    // bf16-converted GEMM weights
    constexpr int nEmb = 512 * 512, nWin = NL * 2 * 1024 * 512, nWx = NL * 2 * 64 * 512,
                  nWout = NL * 2 * 512 * 512, nW1 = NL * DFF * DM, nW2 = NL * DM * DFF,
                  nHead = PRED * DM, nFold = NL * 2 * 512 * 512;
    bf* wEmb  = (bf*)alloc((size_t)nEmb * 2);
    bf* wWin  = (bf*)alloc((size_t)nWin * 2);
    bf* wWx   = (bf*)alloc((size_t)nWx * 2);
    bf* wWout = (bf*)alloc((size_t)nWout * 2);
    bf* wW1   = (bf*)alloc((size_t)nW1 * 2);
    bf* wW2   = (bf*)alloc((size_t)nW2 * 2);
    bf* wHead = (bf*)alloc((size_t)nHead * 2);
    bf* wFold = (bf*)alloc((size_t)nFold * 2);
    size_t fixedEnd = off;

    // adaptive chunk size: CB batches per chunk
    // chunk: xz(Mc*4096) + xc(Mc*2048) + dbc(Mc*256) + y(Mc*2048) + dtc(Mc*4096)
    //        + hloc + aprod
    auto scanScr = [&](size_t cb) { return cb * 2 * 8 * (size_t)NCH * 16 * 64 * 4; };
    int CB = 1;
    {
        int cbs[6] = {32, 16, 8, 4, 2, 1};
        for (int i = 0; i < 6; i++) {
            size_t mc = (size_t)cbs[i] * NTOK;
            size_t chunkB = a256(mc * 4096) + a256(mc * 2048) + a256(mc * 256)
                          + a256(mc * 2048) + a256(mc * 4096) + 2 * a256(scanScr(cbs[i]));
            if (fixedEnd + chunkB <= ws_size) { CB = cbs[i]; break; }
        }
    }
    const size_t Mc = (size_t)CB * NTOK;
    size_t co = fixedEnd;
    bf* xzc = (bf*)(ws + co);        co += a256(Mc * 4096);
    bf* xcc = (bf*)(ws + co);        co += a256(Mc * 2048);
    float* dbcc = (float*)(ws + co); co += a256(Mc * 256);
    bf* ycc = (bf*)(ws + co);        co += a256(Mc * 2048);
    float* dtcc = (float*)(ws + co); co += a256(Mc * 4096);
    float* hloc = (float*)(ws + co); co += a256(scanScr(CB));
    float* aprod = (float*)(ws + co);
    const int NC = BSZ / CB;
    const int MTc = (int)((Mc + 127) / 128);
    constexpr int MT = (M + 127) / 128;  // 217
    const int fixTotal = CB * 2 * 8 * 16 * 64;

    // weight conversion f32 -> bf16, and Wdt·Wx32 fold
    cvt_kernel<<<(nEmb / 4 + 255) / 256, 256, 0, stream>>>(W_emb, wEmb, nEmb / 4);
    cvt_kernel<<<(nWin / 4 + 255) / 256, 256, 0, stream>>>(mWin, wWin, nWin / 4);
    cvt_kernel<<<(nWx / 4 + 255) / 256, 256, 0, stream>>>(mWx, wWx, nWx / 4);
    cvt_kernel<<<(nWout / 4 + 255) / 256, 256, 0, stream>>>(mWout, wWout, nWout / 4);
    cvt_kernel<<<(nW1 / 4 + 255) / 256, 256, 0, stream>>>(W1w, wW1, nW1 / 4);
    cvt_kernel<<<(nW2 / 4 + 255) / 256, 256, 0, stream>>>(W2w, wW2, nW2 / 4);
    cvt_kernel<<<(nHead / 4 + 255) / 256, 256, 0, stream>>>(headW, wHead, nHead / 4);
    fold_kernel<<<nFold / 256, 256, 0, stream>>>(mWdt, mWx, wFold);

    meanstd_kernel<<<dim3(4, BSZ), 256, 0, stream>>>(x_enc, mean, stdv);
    tok_kernel<<<dim3(28, 16, BSZ), dim3(32, 8), 0, stream>>>(x_enc, x_mark, mean, stdv, t1);
    // embedding: h = tok · W_emb^T + b_emb
    gemm_kernel<128, 0, true, false, false, bf><<<dim3(MT, 4), 256, 0, stream>>>(
        t1, nullptr, wEmb, nullptr, h, b_emb, nullptr,
        M, DM, SEQ, SEQ, SEQ, 0, DM, 0, 0, 0, 0, nullptr, nullptr);

    for (int l = 0; l < NL; l++) {
        const bf* Winl = wWin + (size_t)l * 2 * 1024 * 512;
        const float* cwl = mcw + (size_t)l * 2 * DM * 2;
        const float* cbl = mcb + (size_t)l * 2 * DM;
        const bf* WxBC = wWx + (size_t)l * 2 * 64 * 512 + 32 * 512;  // B,C rows only
        const bf* Foldl = wFold + (size_t)l * 2 * 512 * 512;
        const float* bdtl = mbdt + (size_t)l * 2 * DM;
        const float* Alogl = mAlog + (size_t)l * 2 * 512 * 16;
        const float* Dl = mD + (size_t)l * 2 * DM;
        const bf* Woutl = wWout + (size_t)l * 2 * 512 * 512;
        const bf* W1l = wW1 + (size_t)l * DFF * DM;
        const bf* W2l = wW2 + (size_t)l * DM * DFF;

        for (int c = 0; c < NC; c++) {
            size_t coff = (size_t)c * Mc;  // token offset
            // xz = h · [Win_f ; Win_r]^T   (N = 2048)
            gemm_kernel<128, 0, false, false, false, bf><<<dim3(MTc, 16), 256, 0, stream>>>(
                h + coff * DM, nullptr, Winl, nullptr, xzc, nullptr, nullptr,
                (int)Mc, 2048, 512, 512, 512, 0, 2048, 0, 0, 0, 0, nullptr, nullptr);
            // conv + silu (both directions)
            conv_kernel<<<(int)(2 * Mc * 64 / 256), 256, 0, stream>>>(xzc, cwl, cbl, xcc, (int)Mc);
            // dbc(B,C) = xc · WxBC^T  (N=32, f32 out, z = dir)
            gemm_kernel<64, 0, false, false, false, float><<<dim3(MTc, 1, 2), 256, 0, stream>>>(
                xcc, nullptr, WxBC, nullptr, dbcc, nullptr, nullptr,
                (int)Mc, 32, 512, 512, 512, 0, 32,
                Mc * 512, (size_t)64 * 512, Mc * 32, 0, nullptr, nullptr);
            // dt = softplus(xc · Fold^T + bdt)  (N=512, f32 out, z = dir)
            gemm_kernel<128, 2, true, false, false, float><<<dim3(MTc, 4, 2), 256, 0, stream>>>(
                xcc, nullptr, Foldl, nullptr, dtcc, bdtl, nullptr,
                (int)Mc, 512, 512, 512, 512, 0, 512,
                Mc * 512, (size_t)512 * 512, Mc * 512, 512, nullptr, nullptr);
            // chunked scan: A (local) -> B (fix) -> C (final, writes y)
            scan_chunk_kernel<false><<<dim3(8, CB, 2 * NCH), 64, 0, stream>>>(
                dtcc, dbcc, xcc, xzc, Alogl, Dl, hloc, aprod, ycc, (int)Mc);
            scan_fix_kernel<<<(fixTotal + 255) / 256, 256, 0, stream>>>(hloc, aprod, fixTotal);
            scan_chunk_kernel<true><<<dim3(8, CB, 2 * NCH), 64, 0, stream>>>(
                dtcc, dbcc, xcc, xzc, Alogl, Dl, hloc, aprod, ycc, (int)Mc);
            // hsum = h + y_f·Wout_f^T + y_r·Wout_r^T  (K=1024, split at 512)
            gemm_kernel<128, 0, false, true, false, bf><<<dim3(MTc, 4), 256, 0, stream>>>(
                ycc, ycc + 512, Woutl, Woutl + 512 * 512, t1 + coff * DM, nullptr, h + coff * DM,
                (int)Mc, DM, 1024, 1024, 512, 512, DM, 0, 0, 0, 0, nullptr, nullptr);
        }
        ln_kernel<<<M / 4, 256, 0, stream>>>(t1, t2, ln1g + l * DM, ln1b + l * DM);
        // FFN
        gemm_kernel<128, 1, true, false, false, bf><<<dim3(MT, 4), 256, 0, stream>>>(
            t2, nullptr, W1l, nullptr, t1, b1w + l * DFF, nullptr,
            M, DFF, DM, DM, DM, 0, DFF, 0, 0, 0, 0, nullptr, nullptr);
        gemm_kernel<128, 0, true, true, false, bf><<<dim3(MT, 4), 256, 0, stream>>>(
            t1, nullptr, W2l, nullptr, h, b2w + l * DM, t2,
            M, DM, DFF, DFF, DFF, 0, DM, 0, 0, 0, 0, nullptr, nullptr);
        ln_kernel<<<M / 4, 256, 0, stream>>>(h, h, ln2g + l * DM, ln2b + l * DM);
    }

    ln_kernel<<<M / 4, 256, 0, stream>>>(h, t1, lnfg, lnfb);
    // head + de-normalize + scatter to (B, PRED, NVAR), plus loss scalar
    gemm_kernel<128, 0, true, false, true, float><<<dim3(MT, 1), 256, 0, stream>>>(
        t1, nullptr, wHead, nullptr, (float*)d_out, headb, nullptr,
        M, PRED, DM, DM, DM, 0, 1, 0, 0, 0, 0, mean, stdv);
}

// Round 8
// 3342.478 us; speedup vs baseline: 3.5819x; 1.0936x over previous
//
#include <hip/hip_runtime.h>
#include <hip/hip_bf16.h>
#include <cmath>

typedef __bf16 bf;
typedef __bf16 bfrag __attribute__((ext_vector_type(8)));
typedef float  f32x4 __attribute__((ext_vector_type(4)));

constexpr int BSZ = 32, SEQ = 512, NVAR = 862, NMARK = 4, NTOK = 866;
constexpr int DM = 512, DS = 16, DTR = 32, DFF = 512, NL = 4, PRED = 96;
constexpr int M = BSZ * NTOK;              // 27712 tokens
constexpr float EPS = 1e-5f;
constexpr int NCH = 32, CL = 28;           // chunked scan: 32*28 = 896 >= 866
static_assert(NCH * CL >= NTOK, "chunks must cover sequence");

// async global -> LDS, 16B per lane (wave-uniform LDS base + lane*16)
__device__ __forceinline__ void gload16(const void* g, void* l) {
    __builtin_amdgcn_global_load_lds((const __attribute__((address_space(1))) void*)g,
                                     (__attribute__((address_space(3))) void*)l, 16, 0, 0);
}

// ---------------------------------------------------------------- f32 -> bf16
__global__ void cvt_kernel(const float* __restrict__ src, bf* __restrict__ dst, int n4) {
    int i = blockIdx.x * 256 + threadIdx.x;
    if (i >= n4) return;
    f32x4 v = ((const f32x4*)src)[i];
    bf o[4];
    o[0] = (bf)v[0]; o[1] = (bf)v[1]; o[2] = (bf)v[2]; o[3] = (bf)v[3];
    *(uint2*)&dst[i * 4] = *(uint2*)o;
}

// ---------------- build combined dt/bc weight: [ld][544][512] bf16
// rows 0..511: Fold = Wdt(512x32)·Wx[0:32]  ;  rows 512..543: Wx[32:64] (B,C)
__global__ void fold_kernel(const float* __restrict__ Wdt, const float* __restrict__ Wx,
                            bf* __restrict__ out) {
    int idx = blockIdx.x * 256 + threadIdx.x;     // NL*2*544*512 total
    int k = idx & 511; int rest = idx >> 9;
    int row = rest % 544; int ld = rest / 544;
    float s;
    if (row < 512) {
        const float* wd = Wdt + ((size_t)ld * 512 + row) * 32;
        const float* wx = Wx + (size_t)ld * 64 * 512 + k;
        s = 0.f;
#pragma unroll 8
        for (int r = 0; r < 32; r++) s += wd[r] * wx[(size_t)r * 512];
    } else {
        s = Wx[(size_t)ld * 64 * 512 + (size_t)(32 + row - 512) * 512 + k];
    }
    out[((size_t)ld * 544 + row) * 512 + k] = (bf)s;
}

// ---------------------------------------------------------------- mean / std
// 64 vars x 4 time-groups per block, LDS reduce (parallelism over time).
__global__ __launch_bounds__(256) void meanstd_kernel(const float* __restrict__ xe,
                               float* __restrict__ mean, float* __restrict__ stdv) {
    __shared__ float sm[2][4][64];
    int b = blockIdx.y;
    int vl = threadIdx.x & 63;
    int tg = threadIdx.x >> 6;
    int v = blockIdx.x * 64 + vl;
    float s = 0.f, sq = 0.f;
    if (v < NVAR) {
        const float* p = xe + (size_t)b * SEQ * NVAR + (size_t)tg * 128 * NVAR + v;
#pragma unroll 4
        for (int t = 0; t < 128; t++) {
            float x = p[(size_t)t * NVAR];
            s += x; sq += x * x;
        }
    }
    sm[0][tg][vl] = s; sm[1][tg][vl] = sq;
    __syncthreads();
    if (tg == 0 && v < NVAR) {
        s  = sm[0][0][vl] + sm[0][1][vl] + sm[0][2][vl] + sm[0][3][vl];
        sq = sm[1][0][vl] + sm[1][1][vl] + sm[1][2][vl] + sm[1][3][vl];
        float mu = s * (1.f / SEQ);
        float var = sq * (1.f / SEQ) - mu * mu;
        mean[b * NVAR + v] = mu;
        stdv[b * NVAR + v] = sqrtf(var + EPS);
    }
}

// ------------------------------------------------- tok build (transpose+norm)
__global__ void tok_kernel(const float* __restrict__ xe, const float* __restrict__ xm,
                           const float* __restrict__ mean, const float* __restrict__ stdv,
                           bf* __restrict__ tok) {
    __shared__ float tile[32][33];
    int b = blockIdx.z;
    int v0 = blockIdx.x * 32, s0 = blockIdx.y * 32;
    int tx = threadIdx.x, ty = threadIdx.y;  // 32 x 8
    int v = v0 + tx;
    float mu = 0.f, rs = 0.f;
    if (v < NVAR) { mu = mean[b * NVAR + v]; rs = 1.f / stdv[b * NVAR + v]; }
#pragma unroll
    for (int j = 0; j < 4; j++) {
        int s = s0 + ty + j * 8;
        float val = 0.f;
        if (v < NVAR)       val = (xe[((size_t)b * SEQ + s) * NVAR + v] - mu) * rs;
        else if (v < NTOK)  val = xm[((size_t)b * SEQ + s) * NMARK + (v - NVAR)];
        tile[ty + j * 8][tx] = val;
    }
    __syncthreads();
#pragma unroll
    for (int j = 0; j < 4; j++) {
        int n = v0 + ty + j * 8;
        if (n < NTOK)
            tok[((size_t)b * NTOK + n) * SEQ + s0 + tx] = (bf)tile[tx][ty + j * 8];
    }
}

// ---------------------------------------------------------------- GEMM
// C[M,N] = A[M,K](bf16) * W[N,K]^T (bf16), f32 accumulate.
// Staging via global_load_lds (async direct-to-LDS), unpadded layout with
// XOR chunk swizzle (chunk ^= row&7) -> bank-conflict-free reads.
// ACT: 0 none, 1 gelu. DTBC: split epilogue col<512 -> softplus -> C (dt),
// col 512..543 -> C2 (B,C). ksplit splits BOTH A and W at k=ksplit.
template <int BN, int ACT, bool BIAS, bool RES, bool HEAD, bool DTBC, typename CT>
__global__ __launch_bounds__(256, 2) void gemm_kernel(
    const bf* __restrict__ A0, const bf* __restrict__ A1,
    const bf* __restrict__ W0, const bf* __restrict__ W1,
    CT* __restrict__ C, float* __restrict__ C2,
    const float* __restrict__ bias, const bf* __restrict__ res,
    int Mreal, int Nreal, int K, int lda, int ldw, int ksplit, int ldc,
    size_t sAz, size_t sWz, size_t sCz, size_t sC2z, size_t sBiasz,
    const float* __restrict__ mean, const float* __restrict__ stdv) {
    constexpr int BM = 128, BK = 64;
    constexpr int NT = BN / 32;
    __shared__ __align__(16) bf Als[BM * BK];
    __shared__ __align__(16) bf Bls[BN * BK];

    int z = blockIdx.z;
    A0 += (size_t)z * sAz; W0 += (size_t)z * sWz; C += (size_t)z * sCz;
    if (DTBC) C2 += (size_t)z * sC2z;
    if (BIAS) bias += (size_t)z * sBiasz;
    int m0 = blockIdx.x * BM, n0 = blockIdx.y * BN;
    int tid = threadIdx.x, lane = tid & 63, wave = tid >> 6;
    int wm = wave >> 1, wn = wave & 1;
    int q = lane >> 4, ml = lane & 15;
    // staging: lane -> row (lane>>3) within 8-row group; swizzled source chunk
    int srow = lane >> 3;
    int aswz = ((lane & 7) ^ srow) * 8;          // global col offset (elems)
    // fragment read swizzle (chunk ^ row&7), kk folds in via XOR
    int swz = ((q ^ (ml & 7))) * 8;

    f32x4 acc[4][NT];
#pragma unroll
    for (int i = 0; i < 4; i++)
#pragma unroll
        for (int j = 0; j < NT; j++) { acc[i][j][0] = 0.f; acc[i][j][1] = 0.f; acc[i][j][2] = 0.f; acc[i][j][3] = 0.f; }

    for (int kt = 0; kt < K; kt += BK) {
        const bf* ab = (ksplit && kt >= ksplit) ? (A1 + (kt - ksplit)) : (A0 + kt);
        const bf* wb = (ksplit && kt >= ksplit) ? (W1 + (kt - ksplit)) : (W0 + kt);
        // A: 128 rows, 4 instr/wave (8 rows each). Tail rows read ws-interior
        // garbage; row-isolated in MFMA, never stored.
#pragma unroll
        for (int i = 0; i < 4; i++) {
            int r = wave * 32 + i * 8;
            gload16(ab + (size_t)(m0 + r + srow) * lda + aswz, &Als[r * BK]);
        }
#pragma unroll
        for (int i = 0; i < BN / 32; i++) {
            int r = wave * (BN / 4) + i * 8;
            gload16(wb + (size_t)(n0 + r + srow) * ldw + aswz, &Bls[r * BK]);
        }
        __syncthreads();   // drains vmcnt -> LDS valid
#pragma unroll
        for (int kk = 0; kk < BK; kk += 32) {
            bfrag af[4], bff[NT];
#pragma unroll
            for (int i = 0; i < 4; i++)
                af[i] = *(bfrag*)&Als[(wm * 64 + i * 16 + ml) * BK + (swz ^ kk)];
#pragma unroll
            for (int j = 0; j < NT; j++)
                bff[j] = *(bfrag*)&Bls[(wn * (BN / 2) + j * 16 + ml) * BK + (swz ^ kk)];
#pragma unroll
            for (int i = 0; i < 4; i++)
#pragma unroll
                for (int j = 0; j < NT; j++)
                    acc[i][j] = __builtin_amdgcn_mfma_f32_16x16x32_bf16(af[i], bff[j], acc[i][j], 0, 0, 0);
        }
        __syncthreads();   // protect LDS before next iteration's loads
    }

#pragma unroll
    for (int j = 0; j < NT; j++) {
        int col = n0 + wn * (BN / 2) + j * 16 + ml;
        float bv = 0.f;
        if (BIAS && col < Nreal) bv = (!DTBC || col < 512) ? bias[col] : 0.f;
#pragma unroll
        for (int i = 0; i < 4; i++) {
            int rowb = m0 + wm * 64 + i * 16 + q * 4;
#pragma unroll
            for (int r = 0; r < 4; r++) {
                int row = rowb + r;
                if (row >= Mreal || col >= Nreal) continue;
                float x = acc[i][j][r] + bv;
                if (DTBC) {
                    if (col < 512) {
                        x = (x > 20.f) ? x : __logf(1.f + __expf(x));   // softplus
                        C[(size_t)row * 512 + col] = (CT)x;
                    } else {
                        C2[(size_t)row * 32 + (col - 512)] = x;
                    }
                    continue;
                }
                if (ACT == 1) x = 0.5f * x * (1.f + erff(x * 0.70710678118654752f));
                if (RES)      x += (float)res[(size_t)row * DM + col];
                if (HEAD) {
                    int bidx = row / NTOK, n = row - bidx * NTOK;
                    if (n < NVAR) {
                        float sc = stdv[bidx * NVAR + n], mm = mean[bidx * NVAR + n];
                        C[((size_t)bidx * PRED + col) * NVAR + n] = (CT)(x * sc + mm);
                    }
                } else {
                    C[(size_t)row * ldc + col] = (CT)x;
                }
            }
        }
    }
    if (HEAD && blockIdx.x == 0 && blockIdx.y == 0 && tid == 0)
        C[(size_t)BSZ * PRED * NVAR] = (CT)0.f;  // loss_reg = 0
}

// ---------------------------------------------------------------- conv + silu
__global__ void conv_kernel(const bf* __restrict__ xz, const float* __restrict__ cw,
                            const float* __restrict__ cb, bf* __restrict__ xc, int Mc) {
    int id = blockIdx.x * 256 + threadIdx.x;   // 2*Mc*64 total
    int dir = id / (Mc * 64); int rem = id - dir * (Mc * 64);
    int token = rem >> 6; int ch0 = (rem & 63) * 8;
    int t = token % NTOK;
    const bf* xb = xz + (size_t)token * (4 * DM) + dir * (2 * DM) + ch0;
    bfrag xt = *(const bfrag*)xb;
    bfrag xn;
#pragma unroll
    for (int i = 0; i < 8; i++) xn[i] = (bf)0.f;
    int tn = dir ? t + 1 : t - 1;
    if ((unsigned)tn < (unsigned)NTOK)
        xn = *(const bfrag*)(xb + (dir ? (4 * DM) : -(4 * DM)));
    const float2* cwp = (const float2*)cw + ((size_t)dir * DM + ch0);
    const float*  cbp = cb + (size_t)dir * DM + ch0;
    bfrag ov;
#pragma unroll
    for (int jj = 0; jj < 8; jj++) {
        float2 w = cwp[jj];
        float x = (float)xn[jj] * w.x + (float)xt[jj] * w.y + cbp[jj];
        x = x / (1.f + __expf(-x));
        ov[jj] = (bf)x;
    }
    *(bfrag*)(xc + (size_t)dir * Mc * DM + (size_t)token * DM + ch0) = ov;
}

// ---------------------------------------------------------------- chunked scan
template <bool FINAL>
__global__ __launch_bounds__(64) void scan_chunk_kernel(
    const float* __restrict__ dtc, const float* __restrict__ dbc,
    const bf* __restrict__ xc, const bf* __restrict__ xz,
    const float* __restrict__ Alog, const float* __restrict__ Dp,
    float* __restrict__ hloc, float* __restrict__ aprod,
    bf* __restrict__ y, int Mc) {
    __shared__ __align__(16) float row[32];
    int lane = threadIdx.x;
    int dg = blockIdx.x, b = blockIdx.y;
    int zc = blockIdx.z; int dir = zc / NCH, c = zc - dir * NCH;
    int d = dg * 64 + lane;
    int dd = dir * DM + d;
    float A2[16];
    {
        const f32x4* ap = (const f32x4*)(Alog + (size_t)dd * DS);
#pragma unroll
        for (int i = 0; i < 4; i++) {
            f32x4 v = ap[i];
#pragma unroll
            for (int jj = 0; jj < 4; jj++)
                A2[i * 4 + jj] = -__expf(v[jj]) * 1.4426950408889634f;  // *log2e
        }
    }
    float A20 = A2[0];
    bool lc = true;
#pragma unroll
    for (int s = 1; s < 16; s++)
        lc = lc && (fabsf(A2[s] - (s + 1) * A20) <= 1e-4f * fabsf(A2[s]));
    bool fast = (__ballot(lc) == ~0ull);
    float Dd = FINAL ? Dp[dd] : 0.f;

    const size_t sbase = (((((size_t)b * 2 + dir) * 8 + dg) * NCH + c) * 16) * 64 + lane;
    float h[16];
#pragma unroll
    for (int s = 0; s < 16; s++) h[s] = FINAL ? hloc[sbase + (size_t)s * 64] : 0.f;
    float dtsum = 0.f;

    const int t0 = c * CL;
    const int t1e = (t0 + CL < NTOK) ? t0 + CL : NTOK;
    const long step = dir ? -1 : 1;

    const float* dtp = nullptr; const float* bcp = nullptr;
    const bf* xcp = nullptr; const bf* xzp = nullptr; bf* yp = nullptr;
    float dtq = 0.f; f32x4 gq = {0.f, 0.f, 0.f, 0.f}; bf xq = (bf)0.f, zq = (bf)0.f;
    if (t0 < t1e) {
        long tok0 = (long)b * NTOK + (dir ? (NTOK - 1 - t0) : t0);
        dtp = dtc + (size_t)dir * Mc * 512 + (size_t)tok0 * 512 + d;
        bcp = dbc + ((size_t)dir * Mc + (size_t)tok0) * 32;
        xcp = xc + (size_t)dir * Mc * 512 + (size_t)tok0 * 512 + d;
        dtq = *dtp;
        if (lane < 8) gq = ((const f32x4*)bcp)[lane];
        xq = *xcp;
        if (FINAL) {
            xzp = xz + (size_t)tok0 * 2048 + dir * 1024 + 512 + d;
            yp  = y  + (size_t)tok0 * 1024 + dir * 512 + d;
            zq = *xzp;
        }
    }
    const long sdt = step * 512, sbc = step * 32, sxc = step * 512;
    const long sxz = step * 2048, sy = step * 1024;

    for (int t = t0; t < t1e; t++) {
        if (lane < 8) ((f32x4*)row)[lane] = gq;
        float dt = dtq;
        float x = (float)xq;
        float zv = (float)zq;
        bf* ypc = yp;
        if (t + 1 < t1e) {
            dtp += sdt; bcp += sbc; xcp += sxc;
            dtq = *dtp;
            if (lane < 8) gq = ((const f32x4*)bcp)[lane];
            xq = *xcp;
            if (FINAL) { xzp += sxz; zq = *xzp; yp += sy; }
        }
        const f32x4* rv = (const f32x4*)row;
        float dtx = dt * x;
        dtsum += dt;
        float yv = 0.f;
        if (fast) {
            float r = exp2f(dt * A20);
            float rp = 1.f;
#pragma unroll
            for (int i = 0; i < 4; i++) {
                f32x4 Bv = rv[i];
                f32x4 Cv = rv[4 + i];
#pragma unroll
                for (int jj = 0; jj < 4; jj++) {
                    int s = i * 4 + jj;
                    rp *= r;
                    h[s] = rp * h[s] + dtx * Bv[jj];
                    if (FINAL) yv += Cv[jj] * h[s];
                }
            }
        } else {
#pragma unroll
            for (int i = 0; i < 4; i++) {
                f32x4 Bv = rv[i];
                f32x4 Cv = rv[4 + i];
#pragma unroll
                for (int jj = 0; jj < 4; jj++) {
                    int s = i * 4 + jj;
                    float a = exp2f(dt * A2[s]);
                    h[s] = a * h[s] + dtx * Bv[jj];
                    if (FINAL) yv += Cv[jj] * h[s];
                }
            }
        }
        if (FINAL) {
            float sz = zv / (1.f + __expf(-zv));
            *ypc = (bf)((yv + Dd * x) * sz);
        }
    }
    if (!FINAL) {
#pragma unroll
        for (int s = 0; s < 16; s++) {
            hloc[sbase + (size_t)s * 64] = h[s];
            aprod[sbase + (size_t)s * 64] = exp2f(dtsum * A2[s]);
        }
    }
}

// Phase B: combine chunk summaries (serial over NCH chunks per group).
__global__ void scan_fix_kernel(float* __restrict__ hloc, const float* __restrict__ aprod, int total) {
    int tid = blockIdx.x * 256 + threadIdx.x;
    if (tid >= total) return;
    int lane = tid & 63;
    int s = (tid >> 6) & 15;
    int g = tid >> 10;  // (b*2+dir)*8+dg
    size_t i0 = (((size_t)g * NCH) * 16 + s) * 64 + lane;
    float H = 0.f;
#pragma unroll
    for (int c = 0; c < NCH; c++) {
        size_t ix = i0 + (size_t)c * 1024;   // 16*64 per chunk
        float hl = hloc[ix];
        float ap = aprod[ix];
        hloc[ix] = H;
        H = hl + ap * H;
    }
}

// ---------------------------------------------------------------- LayerNorm
__global__ __launch_bounds__(256) void ln_kernel(const bf* X, bf* Y,
                                                 const float* __restrict__ g, const float* __restrict__ bb) {
    int token = blockIdx.x * 4 + (threadIdx.x >> 6);
    int lane = threadIdx.x & 63;
    bfrag xv = *(const bfrag*)(X + (size_t)token * DM + lane * 8);
    float xf[8]; float s = 0.f, sq = 0.f;
#pragma unroll
    for (int j = 0; j < 8; j++) { xf[j] = (float)xv[j]; s += xf[j]; sq += xf[j] * xf[j]; }
#pragma unroll
    for (int o = 1; o < 64; o <<= 1) { s += __shfl_xor(s, o); sq += __shfl_xor(sq, o); }
    float mu = s * (1.f / DM);
    float rs = rsqrtf(sq * (1.f / DM) - mu * mu + EPS);
    f32x4 g0 = ((const f32x4*)g)[lane * 2], g1 = ((const f32x4*)g)[lane * 2 + 1];
    f32x4 b0 = ((const f32x4*)bb)[lane * 2], b1 = ((const f32x4*)bb)[lane * 2 + 1];
    bfrag ov;
#pragma unroll
    for (int j = 0; j < 8; j++) {
        float gg = (j < 4) ? g0[j] : g1[j - 4];
        float bbv = (j < 4) ? b0[j] : b1[j - 4];
        ov[j] = (bf)((xf[j] - mu) * rs * gg + bbv);
    }
    *(bfrag*)(Y + (size_t)token * DM + lane * 8) = ov;
}

// ---------------------------------------------------------------- launch
extern "C" void kernel_launch(void* const* d_in, const int* in_sizes, int n_in,
                              void* d_out, int out_size, void* d_ws, size_t ws_size,
                              hipStream_t stream) {
    const float* x_enc = (const float*)d_in[0];
    const float* x_mark = (const float*)d_in[1];
    const float* W_emb = (const float*)d_in[4];
    const float* b_emb = (const float*)d_in[5];
    const float* mWin = (const float*)d_in[6];
    const float* mcw = (const float*)d_in[7];
    const float* mcb = (const float*)d_in[8];
    const float* mWx = (const float*)d_in[9];
    const float* mWdt = (const float*)d_in[10];
    const float* mbdt = (const float*)d_in[11];
    const float* mAlog = (const float*)d_in[12];
    const float* mD = (const float*)d_in[13];
    const float* mWout = (const float*)d_in[14];
    const float* W1w = (const float*)d_in[15];
    const float* b1w = (const float*)d_in[16];
    const float* W2w = (const float*)d_in[17];
    const float* b2w = (const float*)d_in[18];
    const float* ln1g = (const float*)d_in[19];
    const float* ln1b = (const float*)d_in[20];
    const float* ln2g = (const float*)d_in[21];
    const float* ln2b = (const float*)d_in[22];
    const float* lnfg = (const float*)d_in[23];
    const float* lnfb = (const float*)d_in[24];
    const float* headW = (const float*)d_in[25];
    const float* headb = (const float*)d_in[26];

    auto a256 = [](size_t x) { return (x + 255) & ~(size_t)255; };
    char* ws = (char*)d_ws;
    size_t off = 0;
    auto alloc = [&](size_t n) { size_t r = off; off += a256(n); return ws + r; };
    float* mean = (float*)alloc((size_t)BSZ * NVAR * 4);
    float* stdv = (float*)alloc((size_t)BSZ * NVAR * 4);
    bf* h  = (bf*)alloc((size_t)M * DM * 2);
    bf* t1 = (bf*)alloc((size_t)M * DM * 2);   // tok / hsum / ff
    bf* t2 = (bf*)alloc((size_t)M * DM * 2);   // h2
    // bf16-converted GEMM weights
    constexpr int nEmb = 512 * 512, nWin = NL * 2 * 1024 * 512,
                  nWout = NL * 2 * 512 * 512, nW1 = NL * DFF * DM, nW2 = NL * DM * DFF,
                  nHead = PRED * DM, nComb = NL * 2 * 544 * 512;
    bf* wEmb  = (bf*)alloc((size_t)nEmb * 2);
    bf* wWin  = (bf*)alloc((size_t)nWin * 2);
    bf* wWout = (bf*)alloc((size_t)nWout * 2);
    bf* wW1   = (bf*)alloc((size_t)nW1 * 2);
    bf* wW2   = (bf*)alloc((size_t)nW2 * 2);
    bf* wHead = (bf*)alloc((size_t)nHead * 2);
    bf* wComb = (bf*)alloc((size_t)nComb * 2);
    size_t fixedEnd = off;

    // adaptive chunk size: CB batches per chunk
    auto scanScr = [&](size_t cb) { return cb * 2 * 8 * (size_t)NCH * 16 * 64 * 4; };
    int CB = 1;
    {
        int cbs[6] = {32, 16, 8, 4, 2, 1};
        for (int i = 0; i < 6; i++) {
            size_t mc = (size_t)cbs[i] * NTOK;
            size_t chunkB = a256(mc * 4096) + a256(mc * 2048) + a256(mc * 256)
                          + a256(mc * 2048) + a256(mc * 4096) + 2 * a256(scanScr(cbs[i]));
            if (fixedEnd + chunkB <= ws_size) { CB = cbs[i]; break; }
        }
    }
    const size_t Mc = (size_t)CB * NTOK;
    size_t co = fixedEnd;
    bf* xzc = (bf*)(ws + co);        co += a256(Mc * 4096);
    bf* xcc = (bf*)(ws + co);        co += a256(Mc * 2048);
    float* dbcc = (float*)(ws + co); co += a256(Mc * 256);
    bf* ycc = (bf*)(ws + co);        co += a256(Mc * 2048);
    float* dtcc = (float*)(ws + co); co += a256(Mc * 4096);
    float* hloc = (float*)(ws + co); co += a256(scanScr(CB));
    float* aprod = (float*)(ws + co);
    const int NC = BSZ / CB;
    const int MTc = (int)((Mc + 127) / 128);
    constexpr int MT = (M + 127) / 128;  // 217
    const int fixTotal = CB * 2 * 8 * 16 * 64;

    // weight conversion f32 -> bf16, and combined dt/bc weight build
    cvt_kernel<<<(nEmb / 4 + 255) / 256, 256, 0, stream>>>(W_emb, wEmb, nEmb / 4);
    cvt_kernel<<<(nWin / 4 + 255) / 256, 256, 0, stream>>>(mWin, wWin, nWin / 4);
    cvt_kernel<<<(nWout / 4 + 255) / 256, 256, 0, stream>>>(mWout, wWout, nWout / 4);
    cvt_kernel<<<(nW1 / 4 + 255) / 256, 256, 0, stream>>>(W1w, wW1, nW1 / 4);
    cvt_kernel<<<(nW2 / 4 + 255) / 256, 256, 0, stream>>>(W2w, wW2, nW2 / 4);
    cvt_kernel<<<(nHead / 4 + 255) / 256, 256, 0, stream>>>(headW, wHead, nHead / 4);
    fold_kernel<<<(nComb + 255) / 256, 256, 0, stream>>>(mWdt, mWx, wComb);

    meanstd_kernel<<<dim3(14, BSZ), 256, 0, stream>>>(x_enc, mean, stdv);
    tok_kernel<<<dim3(28, 16, BSZ), dim3(32, 8), 0, stream>>>(x_enc, x_mark, mean, stdv, t1);
    // embedding: h = tok · W_emb^T + b_emb
    gemm_kernel<128, 0, true, false, false, false, bf><<<dim3(MT, 4), 256, 0, stream>>>(
        t1, nullptr, wEmb, nullptr, h, nullptr, b_emb, nullptr,
        M, DM, SEQ, SEQ, SEQ, 0, DM, 0, 0, 0, 0, 0, nullptr, nullptr);

    for (int l = 0; l < NL; l++) {
        const bf* Winl = wWin + (size_t)l * 2 * 1024 * 512;
        const float* cwl = mcw + (size_t)l * 2 * DM * 2;
        const float* cbl = mcb + (size_t)l * 2 * DM;
        const bf* Combl = wComb + (size_t)l * 2 * 544 * 512;
        const float* bdtl = mbdt + (size_t)l * 2 * DM;
        const float* Alogl = mAlog + (size_t)l * 2 * 512 * 16;
        const float* Dl = mD + (size_t)l * 2 * DM;
        const bf* Woutl = wWout + (size_t)l * 2 * 512 * 512;
        const bf* W1l = wW1 + (size_t)l * DFF * DM;
        const bf* W2l = wW2 + (size_t)l * DM * DFF;

        for (int c = 0; c < NC; c++) {
            size_t coff = (size_t)c * Mc;  // token offset
            // xz = h · [Win_f ; Win_r]^T   (N = 2048)
            gemm_kernel<128, 0, false, false, false, false, bf><<<dim3(MTc, 16), 256, 0, stream>>>(
                h + coff * DM, nullptr, Winl, nullptr, xzc, nullptr, nullptr, nullptr,
                (int)Mc, 2048, 512, 512, 512, 0, 2048, 0, 0, 0, 0, 0, nullptr, nullptr);
            // conv + silu (both directions)
            conv_kernel<<<(int)(2 * Mc * 64 / 256), 256, 0, stream>>>(xzc, cwl, cbl, xcc, (int)Mc);
            // fused dt (softplus, N=0..511) + B,C (N=512..543) GEMM, z = dir
            gemm_kernel<128, 0, true, false, false, true, float><<<dim3(MTc, 5, 2), 256, 0, stream>>>(
                xcc, nullptr, Combl, nullptr, dtcc, dbcc, bdtl, nullptr,
                (int)Mc, 544, 512, 512, 512, 0, 512,
                Mc * 512, (size_t)544 * 512, Mc * 512, Mc * 32, 512, nullptr, nullptr);
            // chunked scan: A (local) -> B (fix) -> C (final, writes y)
            scan_chunk_kernel<false><<<dim3(8, CB, 2 * NCH), 64, 0, stream>>>(
                dtcc, dbcc, xcc, xzc, Alogl, Dl, hloc, aprod, ycc, (int)Mc);
            scan_fix_kernel<<<(fixTotal + 255) / 256, 256, 0, stream>>>(hloc, aprod, fixTotal);
            scan_chunk_kernel<true><<<dim3(8, CB, 2 * NCH), 64, 0, stream>>>(
                dtcc, dbcc, xcc, xzc, Alogl, Dl, hloc, aprod, ycc, (int)Mc);
            // hsum = h + y_f·Wout_f^T + y_r·Wout_r^T  (K=1024, split at 512)
            gemm_kernel<128, 0, false, true, false, false, bf><<<dim3(MTc, 4), 256, 0, stream>>>(
                ycc, ycc + 512, Woutl, Woutl + 512 * 512, t1 + coff * DM, nullptr, nullptr, h + coff * DM,
                (int)Mc, DM, 1024, 1024, 512, 512, DM, 0, 0, 0, 0, 0, nullptr, nullptr);
        }
        ln_kernel<<<M / 4, 256, 0, stream>>>(t1, t2, ln1g + l * DM, ln1b + l * DM);
        // FFN
        gemm_kernel<128, 1, true, false, false, false, bf><<<dim3(MT, 4), 256, 0, stream>>>(
            t2, nullptr, W1l, nullptr, t1, nullptr, b1w + l * DFF, nullptr,
            M, DFF, DM, DM, DM, 0, DFF, 0, 0, 0, 0, 0, nullptr, nullptr);
        gemm_kernel<128, 0, true, true, false, false, bf><<<dim3(MT, 4), 256, 0, stream>>>(
            t1, nullptr, W2l, nullptr, h, nullptr, b2w + l * DM, t2,
            M, DM, DFF, DFF, DFF, 0, DM, 0, 0, 0, 0, 0, nullptr, nullptr);
        ln_kernel<<<M / 4, 256, 0, stream>>>(h, h, ln2g + l * DM, ln2b + l * DM);
    }

    ln_kernel<<<M / 4, 256, 0, stream>>>(h, t1, lnfg, lnfb);
    // head + de-normalize + scatter to (B, PRED, NVAR), plus loss scalar
    gemm_kernel<128, 0, true, false, true, false, float><<<dim3(MT, 1), 256, 0, stream>>>(
        t1, nullptr, wHead, nullptr, (float*)d_out, nullptr, headb, nullptr,
        M, PRED, DM, DM, DM, 0, 1, 0, 0, 0, 0, 0, mean, stdv);
}